// Round 20
// baseline (145.201 us; speedup 1.0000x reference)
//
#include <hip/hip_runtime.h>
#include <hip/hip_bf16.h>

// ---------------------------------------------------------------------------
// CompGCN layer:
//   bf16 data plane; coarse-bucket (128 keys) counting sort (low write amp);
//   per-bucket LDS fine sort -> key-sorted payload + per-key CSR;
//   16-lane-group aggregation (4 keys/wave, 4 edge-chains in flight);
//   bf16-MFMA fused 3-way GEMM: 512-thread block, 128 rows x 64-col half,
//   ONE 48KB weight staging then barrier-free per-wave compute;
//   two-stage atomic-free BN reduce; vectorized BN apply + ReLU;
//   out_rel = rel @ w_rel.
// ---------------------------------------------------------------------------

#define SCAN_BLOCK 256
#define CB 128               // keys per coarse bucket
#define CHUNK 4096           // edges per hist/rank block
#define NBC_MAX 800          // >= ceil(2V/CB) = 782
#define CAP 3072             // LDS staging cap per bucket (lambda=1024, 64 sigma)
#define RED1 64              // stage-1 reduce blocks (fixed)

typedef __attribute__((ext_vector_type(8))) short short8v;   // 8 bf16
typedef __attribute__((ext_vector_type(4))) float float4v;   // MFMA C/D

__device__ inline short f2bf(float f) {
    union { float f; unsigned u; } c; c.f = f;
    unsigned u = c.u;
    return (short)((u + 0x7fffu + ((u >> 16) & 1u)) >> 16);  // RNE
}
__device__ inline unsigned packbf(float a, float b) {
    return (unsigned)(unsigned short)f2bf(a) |
           ((unsigned)(unsigned short)f2bf(b) << 16);
}
__device__ inline float bflo(unsigned u) { return __uint_as_float(u << 16); }
__device__ inline float bfhi(unsigned u) { return __uint_as_float(u & 0xffff0000u); }

// cast x [V,128] and rel [R,128] to bf16, 8 elems/thread
__global__ __launch_bounds__(256) void xcast_kernel(
    const float* __restrict__ x, const float* __restrict__ rel,
    short* __restrict__ xbf, short* __restrict__ relbf, int V, int R)
{
    size_t i = ((size_t)blockIdx.x * 256 + threadIdx.x) * 8;
    size_t nx = (size_t)V * 128;
    size_t total = nx + (size_t)R * 128;
    if (i >= total) return;
    const float* sp; short* dp; size_t k;
    if (i < nx) { sp = x; dp = xbf; k = i; }
    else        { sp = rel; dp = relbf; k = i - nx; }
    float4 v0 = *reinterpret_cast<const float4*>(sp + k);
    float4 v1 = *reinterpret_cast<const float4*>(sp + k + 4);
    short8v o;
    o[0] = f2bf(v0.x); o[1] = f2bf(v0.y); o[2] = f2bf(v0.z); o[3] = f2bf(v0.w);
    o[4] = f2bf(v1.x); o[5] = f2bf(v1.y); o[6] = f2bf(v1.z); o[7] = f2bf(v1.w);
    *reinterpret_cast<short8v*>(dp + k) = o;
}

// per-block LDS histogram over coarse buckets; counts stored BLOCK-MAJOR
__global__ __launch_bounds__(256) void hist_coarse_kernel(
    const int* __restrict__ dst, int* __restrict__ counts,
    int E, int V, int NBC)
{
    __shared__ int lh[NBC_MAX];
    for (int i = threadIdx.x; i < NBC; i += 256) lh[i] = 0;
    __syncthreads();
    int half = E >> 1;
    int e0 = blockIdx.x * CHUNK;
    for (int i = 0; i < CHUNK / 256; ++i) {
        int e = e0 + i * 256 + threadIdx.x;
        if (e < E) {
            int key = dst[e] + (e < half ? 0 : V);
            atomicAdd(&lh[key >> 7], 1);
        }
    }
    __syncthreads();
    for (int i = threadIdx.x; i < NBC; i += 256)
        counts[(size_t)blockIdx.x * NBC + i] = lh[i];
}

// scan phase 1, TRANSPOSED read: logical l = bucket*NBLK + blk
__global__ __launch_bounds__(SCAN_BLOCK) void scan_partial_t_kernel(
    const int* __restrict__ cnt_bm, int* __restrict__ partials,
    int CN, int NBC, int NBLK)
{
    __shared__ int red[SCAN_BLOCK];
    int l = blockIdx.x * SCAN_BLOCK + threadIdx.x;
    int v = 0;
    if (l < CN) {
        int bu = l / NBLK, bl = l - bu * NBLK;
        v = cnt_bm[(size_t)bl * NBC + bu];
    }
    red[threadIdx.x] = v;
    __syncthreads();
    for (int s = SCAN_BLOCK / 2; s > 0; s >>= 1) {
        if (threadIdx.x < s) red[threadIdx.x] += red[threadIdx.x + s];
        __syncthreads();
    }
    if (threadIdx.x == 0) partials[blockIdx.x] = red[0];
}

__global__ __launch_bounds__(1024) void scan_top_kernel(
    int* __restrict__ partials, int NB)
{
    __shared__ int sh[1024];
    int t = threadIdx.x;
    sh[t] = (t < NB) ? partials[t] : 0;
    __syncthreads();
    for (int s = 1; s < 1024; s <<= 1) {
        int v = (t >= s) ? sh[t - s] : 0;
        __syncthreads();
        sh[t] += v;
        __syncthreads();
    }
    if (t < NB) partials[t] = (t == 0) ? 0 : sh[t - 1];
}

__global__ __launch_bounds__(SCAN_BLOCK) void scan_final_t_kernel(
    const int* __restrict__ cnt_bm, const int* __restrict__ partials,
    int* __restrict__ base, int CN, int NBC, int NBLK)
{
    __shared__ int sh[SCAN_BLOCK];
    int l = blockIdx.x * SCAN_BLOCK + threadIdx.x;
    int t = threadIdx.x;
    int v = 0;
    if (l < CN) {
        int bu = l / NBLK, bl = l - bu * NBLK;
        v = cnt_bm[(size_t)bl * NBC + bu];
    }
    sh[t] = v;
    __syncthreads();
    for (int s = 1; s < SCAN_BLOCK; s <<= 1) {
        int u = (t >= s) ? sh[t - s] : 0;
        __syncthreads();
        sh[t] += u;
        __syncthreads();
    }
    if (l < CN) base[l] = partials[blockIdx.x] + sh[t] - v;
}

// scatter payload; per-(bucket,block) runs contiguous, written from one CU.
// payload: (src<<16 | type<<8 | key&127, norm-bits)
__global__ __launch_bounds__(256) void rank_coarse_kernel(
    const int* __restrict__ dst,
    const int* __restrict__ src,
    const int* __restrict__ edge_type,
    const float* __restrict__ edge_norm,
    const int* __restrict__ base,
    uint2* __restrict__ pay,
    int E, int V, int NBC, int NBLK)
{
    __shared__ int lh[NBC_MAX];
    __shared__ int lb[NBC_MAX];
    for (int i = threadIdx.x; i < NBC; i += 256) {
        lh[i] = 0;
        lb[i] = base[(size_t)i * NBLK + blockIdx.x];
    }
    __syncthreads();
    int half = E >> 1;
    int e0 = blockIdx.x * CHUNK;
    for (int i = 0; i < CHUNK / 256; ++i) {
        int e = e0 + i * 256 + threadIdx.x;
        if (e < E) {
            int d = dst[e], s = src[e], t = edge_type[e];
            float n = edge_norm[e];
            int key = d + (e < half ? 0 : V);
            int b = key >> 7;
            int r = atomicAdd(&lh[b], 1);
            pay[lb[b] + r] = make_uint2(
                ((unsigned)s << 16) | ((unsigned)t << 8) | (unsigned)(key & 127),
                __float_as_uint(n));
        }
    }
}

// one block per coarse bucket: LDS counting sort of the bucket's payload;
// writes key-sorted pay2 (coalesced) + per-key CSR foffg [NK+1].
__global__ __launch_bounds__(256) void fine_sort_kernel(
    const uint2* __restrict__ pay,
    const int* __restrict__ base,
    uint2* __restrict__ pay2,
    int* __restrict__ foffg,
    int E, int NK, int NBC, int NBLK)
{
    __shared__ uint2 pay_s[CAP];     // 24 KB
    __shared__ int fcnt[CB];
    __shared__ int ssc[CB];
    __shared__ int fcur[CB];

    int b = blockIdx.x;
    int beg = base[(size_t)b * NBLK];
    int end = (b + 1 < NBC) ? base[(size_t)(b + 1) * NBLK] : E;
    int cnt = end - beg;
    int tid = threadIdx.x;

    if (tid < CB) fcnt[tid] = 0;
    __syncthreads();
    for (int j = tid; j < cnt; j += 256)
        atomicAdd(&fcnt[pay[beg + j].x & 127u], 1);
    __syncthreads();
    if (tid < CB) ssc[tid] = fcnt[tid];
    __syncthreads();
    for (int s = 1; s < CB; s <<= 1) {
        int v = 0;
        if (tid < CB && tid >= s) v = ssc[tid - s];
        __syncthreads();
        if (tid < CB) ssc[tid] += v;
        __syncthreads();
    }
    if (tid < CB) {
        int ex = ssc[tid] - fcnt[tid];
        fcur[tid] = ex;
        int key = b * CB + tid;
        if (key <= NK) foffg[key] = beg + ex;
    }
    __syncthreads();

    if (cnt <= CAP) {
        for (int j = tid; j < cnt; j += 256) {
            uint2 p = pay[beg + j];
            int r = atomicAdd(&fcur[p.x & 127u], 1);
            pay_s[r] = p;
        }
        __syncthreads();
        for (int j = tid; j < cnt; j += 256) pay2[beg + j] = pay_s[j];
    } else {
        for (int j = tid; j < cnt; j += 256) {
            uint2 p = pay[beg + j];
            int r = atomicAdd(&fcur[p.x & 127u], 1);
            pay2[beg + r] = p;
        }
    }
}

// 16-lane group per key (4 keys/wave): 4 independent edge-gather chains per
// wave, 16B row loads (8 bf16/lane), branch-free tail predication.
__global__ __launch_bounds__(256) void aggregate_g16_kernel(
    const short* __restrict__ xbf,
    const short* __restrict__ relbf,
    const uint2* __restrict__ pay2,
    const int* __restrict__ foffg,
    short* __restrict__ accbf,       // [NK,128]
    int NK, int E)
{
    int wid = (blockIdx.x * 256 + threadIdx.x) >> 6;
    int lane = threadIdx.x & 63;
    int g = lane >> 4;
    int sub = lane & 15;
    int k = wid * 4 + g;
    if (k >= NK) k = NK - 1;
    int f0 = sub << 3;

    int beg = foffg[k];
    int end = foffg[k + 1];
    int cnt = end - beg;

    int maxc = cnt;
    maxc = max(maxc, __shfl_xor(maxc, 16, 64));
    maxc = max(maxc, __shfl_xor(maxc, 32, 64));

    float a0 = 0.f, a1 = 0.f, a2 = 0.f, a3 = 0.f;
    float a4 = 0.f, a5 = 0.f, a6 = 0.f, a7 = 0.f;

    for (int bas = 0; bas < maxc; bas += 16) {
        int off = bas + sub;
        int cidx = (cnt > 0) ? min(off, cnt - 1) : 0;
        int j = min(beg + cidx, E - 1);
        uint2 p = pay2[j];
        int qmax = min(16, maxc - bas);
        for (int q = 0; q < qmax; ++q) {
            int srcl = (lane & 48) + q;
            unsigned pqx = __shfl(p.x, srcl, 64);
            unsigned pqn = __shfl(p.y, srcl, 64);
            float n = ((bas + q) < cnt) ? __uint_as_float(pqn) : 0.f;
            int s = (int)(pqx >> 16);
            int t = (int)((pqx >> 8) & 0xffu);
            uint4 xv = *reinterpret_cast<const uint4*>(xbf + (size_t)s * 128 + f0);
            uint4 rv = *reinterpret_cast<const uint4*>(relbf + (size_t)t * 128 + f0);
            a0 += bflo(xv.x) * bflo(rv.x) * n;
            a1 += bfhi(xv.x) * bfhi(rv.x) * n;
            a2 += bflo(xv.y) * bflo(rv.y) * n;
            a3 += bfhi(xv.y) * bfhi(rv.y) * n;
            a4 += bflo(xv.z) * bflo(rv.z) * n;
            a5 += bfhi(xv.z) * bfhi(rv.z) * n;
            a6 += bflo(xv.w) * bflo(rv.w) * n;
            a7 += bfhi(xv.w) * bfhi(rv.w) * n;
        }
    }
    uint4 o;
    o.x = packbf(a0, a1);
    o.y = packbf(a2, a3);
    o.z = packbf(a4, a5);
    o.w = packbf(a6, a7);
    *reinterpret_cast<uint4*>(accbf + (size_t)k * 128 + f0) = o;
}

// pack weights into bf16 MFMA B-fragment order; loop_rel folded into loop_w
__global__ __launch_bounds__(256) void wpack_kernel(
    const float* __restrict__ in_w,
    const float* __restrict__ out_w,
    const float* __restrict__ loop_w,
    const float* __restrict__ loop_rel,
    short* __restrict__ wpack)
{
    int idx = blockIdx.x * 256 + threadIdx.x;
    if (idx >= 3 * 8 * 4 * 64) return;
    int lane = idx & 63;
    int t    = (idx >> 6) & 3;
    int cblk = (idx >> 8) & 7;
    int m    = idx >> 11;
    const float* W = (m == 0) ? in_w : (m == 1) ? out_w : loop_w;
    int col = cblk * 16 + (lane & 15);
    int kb  = t * 32 + ((lane >> 4) << 3);
    short8v v;
#pragma unroll
    for (int j = 0; j < 8; ++j) {
        float w = W[(kb + j) * 128 + col];
        if (m == 2) w *= loop_rel[kb + j];
        v[j] = f2bf(w);
    }
    *reinterpret_cast<short8v*>(wpack + (size_t)idx * 8) = v;
}

// bf16 MFMA fused GEMM + bias + /3.
// 512 threads (8 waves) per block; block = 128 rows x 64-col half
// (rb = blockIdx>>1, hh = blockIdx&1). ONE 48KB weight staging (all 3
// matrices for this col-half) + one barrier, then waves run MFMAs
// independently with NO further barriers until the stats epilogue
// (rounds 16-18 lesson: lockstep phases x 3-block/CU grid = latency serial).
__global__ __launch_bounds__(512, 4) void fused_gemm_mfma_kernel(
    const short* __restrict__ accbf,     // [2V,128]
    const short* __restrict__ xbf,       // [V,128]
    const short* __restrict__ wpack,
    const float* __restrict__ bias,
    float* __restrict__ h,
    float* __restrict__ stats_part,      // [NRB][256]
    int V)
{
    __shared__ short wlds[3 * 4 * 4 * 64 * 8];   // 48 KB
    __shared__ float s_red[128];                 // [0:64] sum, [64:128] sumsq

    int tid  = threadIdx.x;
    int wave = tid >> 6;                 // 0..7
    int lane = tid & 63;
    int kgrp = lane >> 4;
    int r16  = lane & 15;
    int rb   = blockIdx.x >> 1;
    int hh   = blockIdx.x & 1;           // column half

    if (tid < 128) s_red[tid] = 0.f;

    // stage this col-half's 3072 short8v fragments: 6 per thread
    {
        const short8v* wsv = reinterpret_cast<const short8v*>(wpack);
        short8v* wldv = reinterpret_cast<short8v*>(wlds);
#pragma unroll
        for (int i = 0; i < 6; ++i) {
            int idx = i * 512 + tid;
            int l  = idx & 63;
            int t  = (idx >> 6) & 3;
            int cb = (idx >> 8) & 3;
            int m  = idx >> 10;
            wldv[idx] = wsv[(((size_t)m * 8 + (4 * hh + cb)) * 4 + t) * 64 + l];
        }
    }

    int row0 = rb * 128 + wave * 16;
    int rowl = row0 + r16;
    int rowc = min(rowl, V - 1);         // clamp (stores guarded)

    // 12 A-fragments, independent loads (issued before the barrier wait)
    short8v af[3][4];
    {
        const short* A0 = accbf + (size_t)rowc * 128;
        const short* A1 = accbf + (size_t)(V + rowc) * 128;
        const short* A2 = xbf + (size_t)rowc * 128;
#pragma unroll
        for (int t = 0; t < 4; ++t) {
            int o = t * 32 + (kgrp << 3);
            af[0][t] = *reinterpret_cast<const short8v*>(A0 + o);
            af[1][t] = *reinterpret_cast<const short8v*>(A1 + o);
            af[2][t] = *reinterpret_cast<const short8v*>(A2 + o);
        }
    }
    __syncthreads();   // weights staged (also: s_red zeroed)

    const short8v* wldv = reinterpret_cast<const short8v*>(wlds);
    float4v c[4];
#pragma unroll
    for (int b = 0; b < 4; ++b) c[b] = (float4v)(0.f);

#pragma unroll
    for (int m = 0; m < 3; ++m)
#pragma unroll
        for (int t = 0; t < 4; ++t) {
#pragma unroll
            for (int b = 0; b < 4; ++b) {
                short8v bf_ = wldv[(((m * 4 + b) * 4) + t) * 64 + lane];
                c[b] = __builtin_amdgcn_mfma_f32_16x16x32_bf16(af[m][t], bf_, c[b], 0, 0, 0);
            }
        }

    // epilogue: C/D layout col=lane&15, row=(lane>>4)*4+r  [m89]
#pragma unroll
    for (int b = 0; b < 4; ++b) {
        int cl  = b * 16 + r16;          // 0..63 local column
        int col = hh * 64 + cl;
        float bv = bias[col];
        float ps = 0.f, pq = 0.f;
#pragma unroll
        for (int r = 0; r < 4; ++r) {
            int row = row0 + kgrp * 4 + r;
            if (row < V) {
                float v = c[b][r] * (1.f / 3.f) + bv;
                h[(size_t)row * 128 + col] = v;
                ps += v;
                pq += v * v;
            }
        }
        atomicAdd(&s_red[cl], ps);
        atomicAdd(&s_red[64 + cl], pq);
    }
    __syncthreads();
    if (tid < 64)
        stats_part[(size_t)rb * 256 + hh * 64 + tid] = s_red[tid];
    else if (tid < 128)
        stats_part[(size_t)rb * 256 + 128 + hh * 64 + (tid - 64)] = s_red[tid];
}

// BN reduce stage 1: 64 blocks, each sums a strided subset of NB partials
__global__ __launch_bounds__(256) void bn_reduce1_kernel(
    const float* __restrict__ stats_part, float* __restrict__ stage, int NB)
{
    int col = threadIdx.x;
    float s = 0.f;
    for (int i = blockIdx.x; i < NB; i += RED1)
        s += stats_part[(size_t)i * 256 + col];
    stage[(size_t)blockIdx.x * 256 + col] = s;
}

// BN reduce stage 2: one block over fixed RED1 partials, fully unrolled
__global__ __launch_bounds__(256) void bn_reduce2_kernel(
    const float* __restrict__ stage, float* __restrict__ stats)
{
    int col = threadIdx.x;
    float s0 = 0.f, s1 = 0.f, s2 = 0.f, s3 = 0.f;
#pragma unroll
    for (int i = 0; i < RED1; i += 4) {
        s0 += stage[(size_t)(i + 0) * 256 + col];
        s1 += stage[(size_t)(i + 1) * 256 + col];
        s2 += stage[(size_t)(i + 2) * 256 + col];
        s3 += stage[(size_t)(i + 3) * 256 + col];
    }
    stats[col] = (s0 + s1) + (s2 + s3);
}

// vectorized BN apply + ReLU: float4 per thread (32 threads/row, 8 rows/iter)
__global__ __launch_bounds__(256) void bn_apply_kernel(
    float* __restrict__ h,
    const float* __restrict__ stats,
    const float* __restrict__ gamma,
    const float* __restrict__ beta,
    int V)
{
    int c4   = (threadIdx.x & 31) << 2;
    int rsub = threadIdx.x >> 5;
    float inv_v = 1.f / (float)V;
    float sc[4], sh[4];
#pragma unroll
    for (int j = 0; j < 4; ++j) {
        int col = c4 + j;
        float mean = stats[col] * inv_v;
        float var  = stats[128 + col] * inv_v - mean * mean;
        float s = rsqrtf(var + 1e-5f) * gamma[col];
        sc[j] = s;
        sh[j] = beta[col] - mean * s;
    }
    for (int row = blockIdx.x * 8 + rsub; row < V; row += gridDim.x * 8) {
        float4 v = *reinterpret_cast<const float4*>(h + (size_t)row * 128 + c4);
        v.x = fmaxf(v.x * sc[0] + sh[0], 0.f);
        v.y = fmaxf(v.y * sc[1] + sh[1], 0.f);
        v.z = fmaxf(v.z * sc[2] + sh[2], 0.f);
        v.w = fmaxf(v.w * sc[3] + sh[3], 0.f);
        *reinterpret_cast<float4*>(h + (size_t)row * 128 + c4) = v;
    }
}

__global__ __launch_bounds__(256) void rel_gemm_kernel(
    const float* __restrict__ rel,
    const float* __restrict__ w_rel,
    float* __restrict__ out_rel,
    int R)
{
    int col = threadIdx.x & 127;
    int row = blockIdx.x * 2 + (threadIdx.x >> 7);
    if (row >= R) return;
    float acc = 0.f;
    for (int k = 0; k < 128; ++k)
        acc += rel[row * 128 + k] * w_rel[k * 128 + col];
    out_rel[row * 128 + col] = acc;
}

extern "C" void kernel_launch(void* const* d_in, const int* in_sizes, int n_in,
                              void* d_out, int out_size, void* d_ws, size_t ws_size,
                              hipStream_t stream)
{
    const float* x         = (const float*)d_in[0];
    const float* rel_repr  = (const float*)d_in[1];
    const float* edge_norm = (const float*)d_in[2];
    const float* in_w      = (const float*)d_in[3];
    const float* out_w     = (const float*)d_in[4];
    const float* loop_w    = (const float*)d_in[5];
    const float* w_rel     = (const float*)d_in[6];
    const float* loop_rel  = (const float*)d_in[7];
    const float* bias      = (const float*)d_in[8];
    const float* bn_gamma  = (const float*)d_in[9];
    const float* bn_beta   = (const float*)d_in[10];
    const int* edge_type   = (const int*)d_in[11];
    const int* src         = (const int*)d_in[12];
    const int* dst         = (const int*)d_in[13];

    const int V = in_sizes[0] / 128;     // 50000
    const int E = in_sizes[2];           // 800000
    const int R = in_sizes[1] / 128;     // 200
    const int NK = 2 * V;                // keys: [dst(in) ; dst(out)]
    const int NBC = (NK + CB - 1) / CB;              // coarse buckets (782)
    const int NBLK = (E + CHUNK - 1) / CHUNK;        // hist/rank blocks (196)
    const int CN = NBC * NBLK;                       // scan length
    const int NB2 = (CN + SCAN_BLOCK - 1) / SCAN_BLOCK;
    const int NRB = (V + 127) / 128;                 // GEMM row blocks (391)

    float* h       = (float*)d_out;              // [V,128]
    float* out_rel = h + (size_t)V * 128;        // [R,128]

    // workspace layout
    char* wp_ = (char*)d_ws;
    short* accbf    = (short*)wp_;  wp_ += (size_t)NK * 128 * sizeof(short);
    short* xbf      = (short*)wp_;  wp_ += (size_t)V * 128 * sizeof(short);
    short* relbf    = (short*)wp_;  wp_ += (size_t)R * 128 * sizeof(short);
    short* wpack    = (short*)wp_;  wp_ += (size_t)3 * 8 * 4 * 64 * 8 * sizeof(short);
    float* stats    = (float*)wp_;  wp_ += 256 * sizeof(float);
    float* stats_pt = (float*)wp_;  wp_ += (size_t)NRB * 256 * sizeof(float);
    float* stage    = (float*)wp_;  wp_ += (size_t)RED1 * 256 * sizeof(float);
    int*   counts   = (int*)wp_;    wp_ += (size_t)CN * sizeof(int);   // block-major
    int*   basep    = (int*)wp_;    wp_ += (size_t)CN * sizeof(int);   // bucket-major
    int*   partials = (int*)wp_;    wp_ += 1024 * sizeof(int);
    int*   foffg    = (int*)wp_;    wp_ += ((size_t)NK + 2) * sizeof(int);
    wp_ = (char*)(((uintptr_t)wp_ + 15) & ~(uintptr_t)15);
    uint2* pay      = (uint2*)wp_;  wp_ += (size_t)E * sizeof(uint2);
    uint2* pay2     = (uint2*)wp_;

    // NOTE: no memset needed — every consumed workspace buffer is fully
    // written each call (stats via two-stage atomic-free reduce; stats_pt
    // rows fully covered by the two col-half blocks per row block).

    {
        size_t total = ((size_t)(V + R) * 128) / 8;
        xcast_kernel<<<(int)((total + 255) / 256), 256, 0, stream>>>(
            x, rel_repr, xbf, relbf, V, R);
    }
    wpack_kernel<<<(3 * 8 * 4 * 64 + 255) / 256, 256, 0, stream>>>(
        in_w, out_w, loop_w, loop_rel, wpack);

    hist_coarse_kernel<<<NBLK, 256, 0, stream>>>(dst, counts, E, V, NBC);
    scan_partial_t_kernel<<<NB2, SCAN_BLOCK, 0, stream>>>(counts, partials, CN, NBC, NBLK);
    scan_top_kernel<<<1, 1024, 0, stream>>>(partials, NB2);
    scan_final_t_kernel<<<NB2, SCAN_BLOCK, 0, stream>>>(counts, partials, basep, CN, NBC, NBLK);
    rank_coarse_kernel<<<NBLK, 256, 0, stream>>>(
        dst, src, edge_type, edge_norm, basep, pay, E, V, NBC, NBLK);
    fine_sort_kernel<<<NBC, 256, 0, stream>>>(
        pay, basep, pay2, foffg, E, NK, NBC, NBLK);

    {
        int waves = (NK + 3) / 4;                        // 25000
        int blocks = (waves * 64 + 255) / 256;           // 6250
        aggregate_g16_kernel<<<blocks, 256, 0, stream>>>(
            xbf, relbf, pay2, foffg, accbf, NK, E);
    }

    fused_gemm_mfma_kernel<<<NRB * 2, 512, 0, stream>>>(
        accbf, xbf, wpack, bias, h, stats_pt, V);

    bn_reduce1_kernel<<<RED1, 256, 0, stream>>>(stats_pt, stage, NRB);
    bn_reduce2_kernel<<<1, 256, 0, stream>>>(stage, stats);
    bn_apply_kernel<<<1024, 256, 0, stream>>>(h, stats, bn_gamma, bn_beta, V);
    rel_gemm_kernel<<<(R + 1) / 2, 256, 0, stream>>>(rel_repr, w_rel, out_rel, R);
}

// Round 21
// 141.872 us; speedup vs baseline: 1.0235x; 1.0235x over previous
//
#include <hip/hip_runtime.h>
#include <hip/hip_bf16.h>

// ---------------------------------------------------------------------------
// CompGCN layer:
//   bf16 data plane; coarse-bucket (128 keys) counting sort (low write amp);
//   per-bucket LDS fine sort -> key-sorted payload + per-key CSR;
//   16-lane-group aggregation (4 keys/wave, 4 edge-chains in flight);
//   bf16-MFMA fused 3-way GEMM (3-phase LDS weights) writing bf16 h
//   (halves GEMM write + BN-apply read bytes); two-stage atomic-free BN
//   reduce; vectorized BN apply + ReLU (bf16 in, f32 out);
//   out_rel = rel @ w_rel.
// ---------------------------------------------------------------------------

#define SCAN_BLOCK 256
#define CB 128               // keys per coarse bucket
#define CHUNK 4096           // edges per hist/rank block
#define NBC_MAX 800          // >= ceil(2V/CB) = 782
#define CAP 3072             // LDS staging cap per bucket (lambda=1024, 64 sigma)
#define RED1 64              // stage-1 reduce blocks (fixed)

typedef __attribute__((ext_vector_type(8))) short short8v;   // 8 bf16
typedef __attribute__((ext_vector_type(4))) float float4v;   // MFMA C/D

__device__ inline short f2bf(float f) {
    union { float f; unsigned u; } c; c.f = f;
    unsigned u = c.u;
    return (short)((u + 0x7fffu + ((u >> 16) & 1u)) >> 16);  // RNE
}
__device__ inline unsigned packbf(float a, float b) {
    return (unsigned)(unsigned short)f2bf(a) |
           ((unsigned)(unsigned short)f2bf(b) << 16);
}
__device__ inline float bflo(unsigned u) { return __uint_as_float(u << 16); }
__device__ inline float bfhi(unsigned u) { return __uint_as_float(u & 0xffff0000u); }

// cast x [V,128] and rel [R,128] to bf16, 8 elems/thread
__global__ __launch_bounds__(256) void xcast_kernel(
    const float* __restrict__ x, const float* __restrict__ rel,
    short* __restrict__ xbf, short* __restrict__ relbf, int V, int R)
{
    size_t i = ((size_t)blockIdx.x * 256 + threadIdx.x) * 8;
    size_t nx = (size_t)V * 128;
    size_t total = nx + (size_t)R * 128;
    if (i >= total) return;
    const float* sp; short* dp; size_t k;
    if (i < nx) { sp = x; dp = xbf; k = i; }
    else        { sp = rel; dp = relbf; k = i - nx; }
    float4 v0 = *reinterpret_cast<const float4*>(sp + k);
    float4 v1 = *reinterpret_cast<const float4*>(sp + k + 4);
    short8v o;
    o[0] = f2bf(v0.x); o[1] = f2bf(v0.y); o[2] = f2bf(v0.z); o[3] = f2bf(v0.w);
    o[4] = f2bf(v1.x); o[5] = f2bf(v1.y); o[6] = f2bf(v1.z); o[7] = f2bf(v1.w);
    *reinterpret_cast<short8v*>(dp + k) = o;
}

// per-block LDS histogram over coarse buckets; counts stored BLOCK-MAJOR
__global__ __launch_bounds__(256) void hist_coarse_kernel(
    const int* __restrict__ dst, int* __restrict__ counts,
    int E, int V, int NBC)
{
    __shared__ int lh[NBC_MAX];
    for (int i = threadIdx.x; i < NBC; i += 256) lh[i] = 0;
    __syncthreads();
    int half = E >> 1;
    int e0 = blockIdx.x * CHUNK;
    for (int i = 0; i < CHUNK / 256; ++i) {
        int e = e0 + i * 256 + threadIdx.x;
        if (e < E) {
            int key = dst[e] + (e < half ? 0 : V);
            atomicAdd(&lh[key >> 7], 1);
        }
    }
    __syncthreads();
    for (int i = threadIdx.x; i < NBC; i += 256)
        counts[(size_t)blockIdx.x * NBC + i] = lh[i];
}

// scan phase 1, TRANSPOSED read: logical l = bucket*NBLK + blk
__global__ __launch_bounds__(SCAN_BLOCK) void scan_partial_t_kernel(
    const int* __restrict__ cnt_bm, int* __restrict__ partials,
    int CN, int NBC, int NBLK)
{
    __shared__ int red[SCAN_BLOCK];
    int l = blockIdx.x * SCAN_BLOCK + threadIdx.x;
    int v = 0;
    if (l < CN) {
        int bu = l / NBLK, bl = l - bu * NBLK;
        v = cnt_bm[(size_t)bl * NBC + bu];
    }
    red[threadIdx.x] = v;
    __syncthreads();
    for (int s = SCAN_BLOCK / 2; s > 0; s >>= 1) {
        if (threadIdx.x < s) red[threadIdx.x] += red[threadIdx.x + s];
        __syncthreads();
    }
    if (threadIdx.x == 0) partials[blockIdx.x] = red[0];
}

__global__ __launch_bounds__(1024) void scan_top_kernel(
    int* __restrict__ partials, int NB)
{
    __shared__ int sh[1024];
    int t = threadIdx.x;
    sh[t] = (t < NB) ? partials[t] : 0;
    __syncthreads();
    for (int s = 1; s < 1024; s <<= 1) {
        int v = (t >= s) ? sh[t - s] : 0;
        __syncthreads();
        sh[t] += v;
        __syncthreads();
    }
    if (t < NB) partials[t] = (t == 0) ? 0 : sh[t - 1];
}

__global__ __launch_bounds__(SCAN_BLOCK) void scan_final_t_kernel(
    const int* __restrict__ cnt_bm, const int* __restrict__ partials,
    int* __restrict__ base, int CN, int NBC, int NBLK)
{
    __shared__ int sh[SCAN_BLOCK];
    int l = blockIdx.x * SCAN_BLOCK + threadIdx.x;
    int t = threadIdx.x;
    int v = 0;
    if (l < CN) {
        int bu = l / NBLK, bl = l - bu * NBLK;
        v = cnt_bm[(size_t)bl * NBC + bu];
    }
    sh[t] = v;
    __syncthreads();
    for (int s = 1; s < SCAN_BLOCK; s <<= 1) {
        int u = (t >= s) ? sh[t - s] : 0;
        __syncthreads();
        sh[t] += u;
        __syncthreads();
    }
    if (l < CN) base[l] = partials[blockIdx.x] + sh[t] - v;
}

// scatter payload; per-(bucket,block) runs contiguous, written from one CU.
// payload: (src<<16 | type<<8 | key&127, norm-bits)
__global__ __launch_bounds__(256) void rank_coarse_kernel(
    const int* __restrict__ dst,
    const int* __restrict__ src,
    const int* __restrict__ edge_type,
    const float* __restrict__ edge_norm,
    const int* __restrict__ base,
    uint2* __restrict__ pay,
    int E, int V, int NBC, int NBLK)
{
    __shared__ int lh[NBC_MAX];
    __shared__ int lb[NBC_MAX];
    for (int i = threadIdx.x; i < NBC; i += 256) {
        lh[i] = 0;
        lb[i] = base[(size_t)i * NBLK + blockIdx.x];
    }
    __syncthreads();
    int half = E >> 1;
    int e0 = blockIdx.x * CHUNK;
    for (int i = 0; i < CHUNK / 256; ++i) {
        int e = e0 + i * 256 + threadIdx.x;
        if (e < E) {
            int d = dst[e], s = src[e], t = edge_type[e];
            float n = edge_norm[e];
            int key = d + (e < half ? 0 : V);
            int b = key >> 7;
            int r = atomicAdd(&lh[b], 1);
            pay[lb[b] + r] = make_uint2(
                ((unsigned)s << 16) | ((unsigned)t << 8) | (unsigned)(key & 127),
                __float_as_uint(n));
        }
    }
}

// one block per coarse bucket: LDS counting sort of the bucket's payload;
// writes key-sorted pay2 (coalesced) + per-key CSR foffg [NK+1].
__global__ __launch_bounds__(256) void fine_sort_kernel(
    const uint2* __restrict__ pay,
    const int* __restrict__ base,
    uint2* __restrict__ pay2,
    int* __restrict__ foffg,
    int E, int NK, int NBC, int NBLK)
{
    __shared__ uint2 pay_s[CAP];     // 24 KB
    __shared__ int fcnt[CB];
    __shared__ int ssc[CB];
    __shared__ int fcur[CB];

    int b = blockIdx.x;
    int beg = base[(size_t)b * NBLK];
    int end = (b + 1 < NBC) ? base[(size_t)(b + 1) * NBLK] : E;
    int cnt = end - beg;
    int tid = threadIdx.x;

    if (tid < CB) fcnt[tid] = 0;
    __syncthreads();
    for (int j = tid; j < cnt; j += 256)
        atomicAdd(&fcnt[pay[beg + j].x & 127u], 1);
    __syncthreads();
    if (tid < CB) ssc[tid] = fcnt[tid];
    __syncthreads();
    for (int s = 1; s < CB; s <<= 1) {
        int v = 0;
        if (tid < CB && tid >= s) v = ssc[tid - s];
        __syncthreads();
        if (tid < CB) ssc[tid] += v;
        __syncthreads();
    }
    if (tid < CB) {
        int ex = ssc[tid] - fcnt[tid];
        fcur[tid] = ex;
        int key = b * CB + tid;
        if (key <= NK) foffg[key] = beg + ex;
    }
    __syncthreads();

    if (cnt <= CAP) {
        for (int j = tid; j < cnt; j += 256) {
            uint2 p = pay[beg + j];
            int r = atomicAdd(&fcur[p.x & 127u], 1);
            pay_s[r] = p;
        }
        __syncthreads();
        for (int j = tid; j < cnt; j += 256) pay2[beg + j] = pay_s[j];
    } else {
        for (int j = tid; j < cnt; j += 256) {
            uint2 p = pay[beg + j];
            int r = atomicAdd(&fcur[p.x & 127u], 1);
            pay2[beg + r] = p;
        }
    }
}

// 16-lane group per key (4 keys/wave): 4 independent edge-gather chains per
// wave, 16B row loads (8 bf16/lane), branch-free tail predication.
__global__ __launch_bounds__(256) void aggregate_g16_kernel(
    const short* __restrict__ xbf,
    const short* __restrict__ relbf,
    const uint2* __restrict__ pay2,
    const int* __restrict__ foffg,
    short* __restrict__ accbf,       // [NK,128]
    int NK, int E)
{
    int wid = (blockIdx.x * 256 + threadIdx.x) >> 6;
    int lane = threadIdx.x & 63;
    int g = lane >> 4;
    int sub = lane & 15;
    int k = wid * 4 + g;
    if (k >= NK) k = NK - 1;
    int f0 = sub << 3;

    int beg = foffg[k];
    int end = foffg[k + 1];
    int cnt = end - beg;

    int maxc = cnt;
    maxc = max(maxc, __shfl_xor(maxc, 16, 64));
    maxc = max(maxc, __shfl_xor(maxc, 32, 64));

    float a0 = 0.f, a1 = 0.f, a2 = 0.f, a3 = 0.f;
    float a4 = 0.f, a5 = 0.f, a6 = 0.f, a7 = 0.f;

    for (int bas = 0; bas < maxc; bas += 16) {
        int off = bas + sub;
        int cidx = (cnt > 0) ? min(off, cnt - 1) : 0;
        int j = min(beg + cidx, E - 1);
        uint2 p = pay2[j];
        int qmax = min(16, maxc - bas);
        for (int q = 0; q < qmax; ++q) {
            int srcl = (lane & 48) + q;
            unsigned pqx = __shfl(p.x, srcl, 64);
            unsigned pqn = __shfl(p.y, srcl, 64);
            float n = ((bas + q) < cnt) ? __uint_as_float(pqn) : 0.f;
            int s = (int)(pqx >> 16);
            int t = (int)((pqx >> 8) & 0xffu);
            uint4 xv = *reinterpret_cast<const uint4*>(xbf + (size_t)s * 128 + f0);
            uint4 rv = *reinterpret_cast<const uint4*>(relbf + (size_t)t * 128 + f0);
            a0 += bflo(xv.x) * bflo(rv.x) * n;
            a1 += bfhi(xv.x) * bfhi(rv.x) * n;
            a2 += bflo(xv.y) * bflo(rv.y) * n;
            a3 += bfhi(xv.y) * bfhi(rv.y) * n;
            a4 += bflo(xv.z) * bflo(rv.z) * n;
            a5 += bfhi(xv.z) * bfhi(rv.z) * n;
            a6 += bflo(xv.w) * bflo(rv.w) * n;
            a7 += bfhi(xv.w) * bfhi(rv.w) * n;
        }
    }
    uint4 o;
    o.x = packbf(a0, a1);
    o.y = packbf(a2, a3);
    o.z = packbf(a4, a5);
    o.w = packbf(a6, a7);
    *reinterpret_cast<uint4*>(accbf + (size_t)k * 128 + f0) = o;
}

// pack weights into bf16 MFMA B-fragment order; loop_rel folded into loop_w
__global__ __launch_bounds__(256) void wpack_kernel(
    const float* __restrict__ in_w,
    const float* __restrict__ out_w,
    const float* __restrict__ loop_w,
    const float* __restrict__ loop_rel,
    short* __restrict__ wpack)
{
    int idx = blockIdx.x * 256 + threadIdx.x;
    if (idx >= 3 * 8 * 4 * 64) return;
    int lane = idx & 63;
    int t    = (idx >> 6) & 3;
    int cblk = (idx >> 8) & 7;
    int m    = idx >> 11;
    const float* W = (m == 0) ? in_w : (m == 1) ? out_w : loop_w;
    int col = cblk * 16 + (lane & 15);
    int kb  = t * 32 + ((lane >> 4) << 3);
    short8v v;
#pragma unroll
    for (int j = 0; j < 8; ++j) {
        float w = W[(kb + j) * 128 + col];
        if (m == 2) w *= loop_rel[kb + j];
        v[j] = f2bf(w);
    }
    *reinterpret_cast<short8v*>(wpack + (size_t)idx * 8) = v;
}

// bf16 MFMA fused GEMM + bias + /3; 3-phase 32KB LDS weight staging;
// h written as bf16 (halves write bytes); BN stats from f32 registers.
__global__ __launch_bounds__(256) void fused_gemm_mfma_kernel(
    const short* __restrict__ accbf,     // [2V,128]
    const short* __restrict__ xbf,       // [V,128]
    const short* __restrict__ wpack,
    const float* __restrict__ bias,
    short* __restrict__ hbf,             // [V,128] bf16 intermediate
    float* __restrict__ stats_part,      // [gridDim.x][256]
    int V)
{
    __shared__ short wlds[8 * 4 * 64 * 8];   // 32 KB: one weight matrix
    __shared__ float s_red[256];

    int tid  = threadIdx.x;
    int wave = tid >> 6;
    int lane = tid & 63;
    int kgrp = lane >> 4;
    int row0 = blockIdx.x * 64 + wave * 16;
    int rowl = row0 + (lane & 15);
    int rowc = min(rowl, V - 1);          // clamp (stores guarded)

    s_red[tid] = 0.f;

    // preload all 12 A-fragments (issued back-to-back)
    short8v af[3][4];
    {
        const short* A0 = accbf + (size_t)rowc * 128;
        const short* A1 = accbf + (size_t)(V + rowc) * 128;
        const short* A2 = xbf + (size_t)rowc * 128;
#pragma unroll
        for (int t = 0; t < 4; ++t) {
            int o = t * 32 + (kgrp << 3);
            af[0][t] = *reinterpret_cast<const short8v*>(A0 + o);
            af[1][t] = *reinterpret_cast<const short8v*>(A1 + o);
            af[2][t] = *reinterpret_cast<const short8v*>(A2 + o);
        }
    }

    float4v c[8];
#pragma unroll
    for (int b = 0; b < 8; ++b) c[b] = (float4v)(0.f);

    for (int m = 0; m < 3; ++m) {
        __syncthreads();
        const short8v* wsrc = reinterpret_cast<const short8v*>(wpack + (size_t)m * 8 * 4 * 64 * 8);
        short8v* wdst = reinterpret_cast<short8v*>(wlds);
#pragma unroll
        for (int i = 0; i < 8; ++i)
            wdst[i * 256 + tid] = wsrc[i * 256 + tid];
        __syncthreads();
#pragma unroll
        for (int t = 0; t < 4; ++t) {
#pragma unroll
            for (int b = 0; b < 8; ++b) {
                short8v bf_ = *reinterpret_cast<const short8v*>(wlds + (((b << 2) + t) * 64 + lane) * 8);
                c[b] = __builtin_amdgcn_mfma_f32_16x16x32_bf16(af[m][t], bf_, c[b], 0, 0, 0);
            }
        }
    }
    __syncthreads();

    // epilogue: C/D layout col=lane&15, row=(lane>>4)*4+r  [m89]
#pragma unroll
    for (int b = 0; b < 8; ++b) {
        int col = b * 16 + (lane & 15);
        float bv = bias[col];
        float ps = 0.f, pq = 0.f;
#pragma unroll
        for (int r = 0; r < 4; ++r) {
            int row = row0 + kgrp * 4 + r;
            if (row < V) {
                float v = c[b][r] * (1.f / 3.f) + bv;
                hbf[(size_t)row * 128 + col] = f2bf(v);
                ps += v;
                pq += v * v;
            }
        }
        atomicAdd(&s_red[col], ps);
        atomicAdd(&s_red[128 + col], pq);
    }
    __syncthreads();
    stats_part[(size_t)blockIdx.x * 256 + tid] = s_red[tid];
}

// BN reduce stage 1: 64 blocks, each sums a strided subset of NB partials
__global__ __launch_bounds__(256) void bn_reduce1_kernel(
    const float* __restrict__ stats_part, float* __restrict__ stage, int NB)
{
    int col = threadIdx.x;
    float s = 0.f;
    for (int i = blockIdx.x; i < NB; i += RED1)
        s += stats_part[(size_t)i * 256 + col];
    stage[(size_t)blockIdx.x * 256 + col] = s;
}

// BN reduce stage 2: one block over fixed RED1 partials, fully unrolled
__global__ __launch_bounds__(256) void bn_reduce2_kernel(
    const float* __restrict__ stage, float* __restrict__ stats)
{
    int col = threadIdx.x;
    float s0 = 0.f, s1 = 0.f, s2 = 0.f, s3 = 0.f;
#pragma unroll
    for (int i = 0; i < RED1; i += 4) {
        s0 += stage[(size_t)(i + 0) * 256 + col];
        s1 += stage[(size_t)(i + 1) * 256 + col];
        s2 += stage[(size_t)(i + 2) * 256 + col];
        s3 += stage[(size_t)(i + 3) * 256 + col];
    }
    stats[col] = (s0 + s1) + (s2 + s3);
}

// vectorized BN apply + ReLU: bf16 in (uint2 = 4 bf16), f32 out (float4)
__global__ __launch_bounds__(256) void bn_apply_kernel(
    const short* __restrict__ hbf,
    float* __restrict__ hout,
    const float* __restrict__ stats,
    const float* __restrict__ gamma,
    const float* __restrict__ beta,
    int V)
{
    int c4   = (threadIdx.x & 31) << 2;
    int rsub = threadIdx.x >> 5;
    float inv_v = 1.f / (float)V;
    float sc[4], sh[4];
#pragma unroll
    for (int j = 0; j < 4; ++j) {
        int col = c4 + j;
        float mean = stats[col] * inv_v;
        float var  = stats[128 + col] * inv_v - mean * mean;
        float s = rsqrtf(var + 1e-5f) * gamma[col];
        sc[j] = s;
        sh[j] = beta[col] - mean * s;
    }
    for (int row = blockIdx.x * 8 + rsub; row < V; row += gridDim.x * 8) {
        uint2 u = *reinterpret_cast<const uint2*>(hbf + (size_t)row * 128 + c4);
        float4 v;
        v.x = fmaxf(bflo(u.x) * sc[0] + sh[0], 0.f);
        v.y = fmaxf(bfhi(u.x) * sc[1] + sh[1], 0.f);
        v.z = fmaxf(bflo(u.y) * sc[2] + sh[2], 0.f);
        v.w = fmaxf(bfhi(u.y) * sc[3] + sh[3], 0.f);
        *reinterpret_cast<float4*>(hout + (size_t)row * 128 + c4) = v;
    }
}

__global__ __launch_bounds__(256) void rel_gemm_kernel(
    const float* __restrict__ rel,
    const float* __restrict__ w_rel,
    float* __restrict__ out_rel,
    int R)
{
    int col = threadIdx.x & 127;
    int row = blockIdx.x * 2 + (threadIdx.x >> 7);
    if (row >= R) return;
    float acc = 0.f;
    for (int k = 0; k < 128; ++k)
        acc += rel[row * 128 + k] * w_rel[k * 128 + col];
    out_rel[row * 128 + col] = acc;
}

extern "C" void kernel_launch(void* const* d_in, const int* in_sizes, int n_in,
                              void* d_out, int out_size, void* d_ws, size_t ws_size,
                              hipStream_t stream)
{
    const float* x         = (const float*)d_in[0];
    const float* rel_repr  = (const float*)d_in[1];
    const float* edge_norm = (const float*)d_in[2];
    const float* in_w      = (const float*)d_in[3];
    const float* out_w     = (const float*)d_in[4];
    const float* loop_w    = (const float*)d_in[5];
    const float* w_rel     = (const float*)d_in[6];
    const float* loop_rel  = (const float*)d_in[7];
    const float* bias      = (const float*)d_in[8];
    const float* bn_gamma  = (const float*)d_in[9];
    const float* bn_beta   = (const float*)d_in[10];
    const int* edge_type   = (const int*)d_in[11];
    const int* src         = (const int*)d_in[12];
    const int* dst         = (const int*)d_in[13];

    const int V = in_sizes[0] / 128;     // 50000
    const int E = in_sizes[2];           // 800000
    const int R = in_sizes[1] / 128;     // 200
    const int NK = 2 * V;                // keys: [dst(in) ; dst(out)]
    const int NBC = (NK + CB - 1) / CB;              // coarse buckets (782)
    const int NBLK = (E + CHUNK - 1) / CHUNK;        // hist/rank blocks (196)
    const int CN = NBC * NBLK;                       // scan length
    const int NB2 = (CN + SCAN_BLOCK - 1) / SCAN_BLOCK;
    const int GEMM_NB = (V + 63) / 64;               // GEMM blocks (782)

    float* hout    = (float*)d_out;              // [V,128]
    float* out_rel = hout + (size_t)V * 128;     // [R,128]

    // workspace layout
    char* wp_ = (char*)d_ws;
    short* accbf    = (short*)wp_;  wp_ += (size_t)NK * 128 * sizeof(short);
    short* xbf      = (short*)wp_;  wp_ += (size_t)V * 128 * sizeof(short);
    short* relbf    = (short*)wp_;  wp_ += (size_t)R * 128 * sizeof(short);
    short* hbf      = (short*)wp_;  wp_ += (size_t)V * 128 * sizeof(short);
    short* wpack    = (short*)wp_;  wp_ += (size_t)3 * 8 * 4 * 64 * 8 * sizeof(short);
    float* stats    = (float*)wp_;  wp_ += 256 * sizeof(float);
    float* stats_pt = (float*)wp_;  wp_ += (size_t)GEMM_NB * 256 * sizeof(float);
    float* stage    = (float*)wp_;  wp_ += (size_t)RED1 * 256 * sizeof(float);
    int*   counts   = (int*)wp_;    wp_ += (size_t)CN * sizeof(int);   // block-major
    int*   basep    = (int*)wp_;    wp_ += (size_t)CN * sizeof(int);   // bucket-major
    int*   partials = (int*)wp_;    wp_ += 1024 * sizeof(int);
    int*   foffg    = (int*)wp_;    wp_ += ((size_t)NK + 2) * sizeof(int);
    wp_ = (char*)(((uintptr_t)wp_ + 15) & ~(uintptr_t)15);
    uint2* pay      = (uint2*)wp_;  wp_ += (size_t)E * sizeof(uint2);
    uint2* pay2     = (uint2*)wp_;

    // NOTE: no memset needed — every consumed workspace buffer is fully
    // written each call (stats via two-stage atomic-free reduce).

    {
        size_t total = ((size_t)(V + R) * 128) / 8;
        xcast_kernel<<<(int)((total + 255) / 256), 256, 0, stream>>>(
            x, rel_repr, xbf, relbf, V, R);
    }
    wpack_kernel<<<(3 * 8 * 4 * 64 + 255) / 256, 256, 0, stream>>>(
        in_w, out_w, loop_w, loop_rel, wpack);

    hist_coarse_kernel<<<NBLK, 256, 0, stream>>>(dst, counts, E, V, NBC);
    scan_partial_t_kernel<<<NB2, SCAN_BLOCK, 0, stream>>>(counts, partials, CN, NBC, NBLK);
    scan_top_kernel<<<1, 1024, 0, stream>>>(partials, NB2);
    scan_final_t_kernel<<<NB2, SCAN_BLOCK, 0, stream>>>(counts, partials, basep, CN, NBC, NBLK);
    rank_coarse_kernel<<<NBLK, 256, 0, stream>>>(
        dst, src, edge_type, edge_norm, basep, pay, E, V, NBC, NBLK);
    fine_sort_kernel<<<NBC, 256, 0, stream>>>(
        pay, basep, pay2, foffg, E, NK, NBC, NBLK);

    {
        int waves = (NK + 3) / 4;                        // 25000
        int blocks = (waves * 64 + 255) / 256;           // 6250
        aggregate_g16_kernel<<<blocks, 256, 0, stream>>>(
            xbf, relbf, pay2, foffg, accbf, NK, E);
    }

    fused_gemm_mfma_kernel<<<GEMM_NB, 256, 0, stream>>>(
        accbf, xbf, wpack, bias, hbf, stats_pt, V);

    bn_reduce1_kernel<<<RED1, 256, 0, stream>>>(stats_pt, stage, GEMM_NB);
    bn_reduce2_kernel<<<1, 256, 0, stream>>>(stage, stats);
    bn_apply_kernel<<<1024, 256, 0, stream>>>(hbf, hout, stats, bn_gamma, bn_beta, V);
    rel_gemm_kernel<<<(R + 1) / 2, 256, 0, stream>>>(rel_repr, w_rel, out_rel, R);
}

// Round 22
// 124.505 us; speedup vs baseline: 1.1662x; 1.1395x over previous
//
#include <hip/hip_runtime.h>
#include <hip/hip_bf16.h>

// ---------------------------------------------------------------------------
// CompGCN layer:
//   bf16 data plane; coarse-bucket (128 keys) counting sort (low write amp);
//   per-bucket LDS fine sort -> key-sorted payload + per-key CSR;
//   16-lane-group aggregation (4 keys/wave, 4 edge-chains in flight);
//   bf16-MFMA fused 3-way GEMM: persistent blocks (1/CU), 48KB weights
//   staged ONCE, multi-row-tile loop with ZERO barriers (fixed block cost
//   amortized over ~4 tiles); bf16 h; two-stage atomic-free BN reduce;
//   vectorized BN apply + ReLU; out_rel = rel @ w_rel.
// ---------------------------------------------------------------------------

#define SCAN_BLOCK 256
#define CB 128               // keys per coarse bucket
#define CHUNK 4096           // edges per hist/rank block
#define NBC_MAX 800          // >= ceil(2V/CB) = 782
#define CAP 3072             // LDS staging cap per bucket (lambda=1024, 64 sigma)
#define RED1 64              // stage-1 reduce blocks (fixed)
#define NGB 128              // GEMM row-group blocks per column half

typedef __attribute__((ext_vector_type(8))) short short8v;   // 8 bf16
typedef __attribute__((ext_vector_type(4))) float float4v;   // MFMA C/D

__device__ inline short f2bf(float f) {
    union { float f; unsigned u; } c; c.f = f;
    unsigned u = c.u;
    return (short)((u + 0x7fffu + ((u >> 16) & 1u)) >> 16);  // RNE
}
__device__ inline unsigned packbf(float a, float b) {
    return (unsigned)(unsigned short)f2bf(a) |
           ((unsigned)(unsigned short)f2bf(b) << 16);
}
__device__ inline float bflo(unsigned u) { return __uint_as_float(u << 16); }
__device__ inline float bfhi(unsigned u) { return __uint_as_float(u & 0xffff0000u); }

// cast x [V,128] and rel [R,128] to bf16, 8 elems/thread
__global__ __launch_bounds__(256) void xcast_kernel(
    const float* __restrict__ x, const float* __restrict__ rel,
    short* __restrict__ xbf, short* __restrict__ relbf, int V, int R)
{
    size_t i = ((size_t)blockIdx.x * 256 + threadIdx.x) * 8;
    size_t nx = (size_t)V * 128;
    size_t total = nx + (size_t)R * 128;
    if (i >= total) return;
    const float* sp; short* dp; size_t k;
    if (i < nx) { sp = x; dp = xbf; k = i; }
    else        { sp = rel; dp = relbf; k = i - nx; }
    float4 v0 = *reinterpret_cast<const float4*>(sp + k);
    float4 v1 = *reinterpret_cast<const float4*>(sp + k + 4);
    short8v o;
    o[0] = f2bf(v0.x); o[1] = f2bf(v0.y); o[2] = f2bf(v0.z); o[3] = f2bf(v0.w);
    o[4] = f2bf(v1.x); o[5] = f2bf(v1.y); o[6] = f2bf(v1.z); o[7] = f2bf(v1.w);
    *reinterpret_cast<short8v*>(dp + k) = o;
}

// per-block LDS histogram over coarse buckets; counts stored BLOCK-MAJOR
__global__ __launch_bounds__(256) void hist_coarse_kernel(
    const int* __restrict__ dst, int* __restrict__ counts,
    int E, int V, int NBC)
{
    __shared__ int lh[NBC_MAX];
    for (int i = threadIdx.x; i < NBC; i += 256) lh[i] = 0;
    __syncthreads();
    int half = E >> 1;
    int e0 = blockIdx.x * CHUNK;
    for (int i = 0; i < CHUNK / 256; ++i) {
        int e = e0 + i * 256 + threadIdx.x;
        if (e < E) {
            int key = dst[e] + (e < half ? 0 : V);
            atomicAdd(&lh[key >> 7], 1);
        }
    }
    __syncthreads();
    for (int i = threadIdx.x; i < NBC; i += 256)
        counts[(size_t)blockIdx.x * NBC + i] = lh[i];
}

// scan phase 1, TRANSPOSED read: logical l = bucket*NBLK + blk
__global__ __launch_bounds__(SCAN_BLOCK) void scan_partial_t_kernel(
    const int* __restrict__ cnt_bm, int* __restrict__ partials,
    int CN, int NBC, int NBLK)
{
    __shared__ int red[SCAN_BLOCK];
    int l = blockIdx.x * SCAN_BLOCK + threadIdx.x;
    int v = 0;
    if (l < CN) {
        int bu = l / NBLK, bl = l - bu * NBLK;
        v = cnt_bm[(size_t)bl * NBC + bu];
    }
    red[threadIdx.x] = v;
    __syncthreads();
    for (int s = SCAN_BLOCK / 2; s > 0; s >>= 1) {
        if (threadIdx.x < s) red[threadIdx.x] += red[threadIdx.x + s];
        __syncthreads();
    }
    if (threadIdx.x == 0) partials[blockIdx.x] = red[0];
}

__global__ __launch_bounds__(1024) void scan_top_kernel(
    int* __restrict__ partials, int NB)
{
    __shared__ int sh[1024];
    int t = threadIdx.x;
    sh[t] = (t < NB) ? partials[t] : 0;
    __syncthreads();
    for (int s = 1; s < 1024; s <<= 1) {
        int v = (t >= s) ? sh[t - s] : 0;
        __syncthreads();
        sh[t] += v;
        __syncthreads();
    }
    if (t < NB) partials[t] = (t == 0) ? 0 : sh[t - 1];
}

__global__ __launch_bounds__(SCAN_BLOCK) void scan_final_t_kernel(
    const int* __restrict__ cnt_bm, const int* __restrict__ partials,
    int* __restrict__ base, int CN, int NBC, int NBLK)
{
    __shared__ int sh[SCAN_BLOCK];
    int l = blockIdx.x * SCAN_BLOCK + threadIdx.x;
    int t = threadIdx.x;
    int v = 0;
    if (l < CN) {
        int bu = l / NBLK, bl = l - bu * NBLK;
        v = cnt_bm[(size_t)bl * NBC + bu];
    }
    sh[t] = v;
    __syncthreads();
    for (int s = 1; s < SCAN_BLOCK; s <<= 1) {
        int u = (t >= s) ? sh[t - s] : 0;
        __syncthreads();
        sh[t] += u;
        __syncthreads();
    }
    if (l < CN) base[l] = partials[blockIdx.x] + sh[t] - v;
}

// scatter payload; per-(bucket,block) runs contiguous, written from one CU.
// payload: (src<<16 | type<<8 | key&127, norm-bits)
__global__ __launch_bounds__(256) void rank_coarse_kernel(
    const int* __restrict__ dst,
    const int* __restrict__ src,
    const int* __restrict__ edge_type,
    const float* __restrict__ edge_norm,
    const int* __restrict__ base,
    uint2* __restrict__ pay,
    int E, int V, int NBC, int NBLK)
{
    __shared__ int lh[NBC_MAX];
    __shared__ int lb[NBC_MAX];
    for (int i = threadIdx.x; i < NBC; i += 256) {
        lh[i] = 0;
        lb[i] = base[(size_t)i * NBLK + blockIdx.x];
    }
    __syncthreads();
    int half = E >> 1;
    int e0 = blockIdx.x * CHUNK;
    for (int i = 0; i < CHUNK / 256; ++i) {
        int e = e0 + i * 256 + threadIdx.x;
        if (e < E) {
            int d = dst[e], s = src[e], t = edge_type[e];
            float n = edge_norm[e];
            int key = d + (e < half ? 0 : V);
            int b = key >> 7;
            int r = atomicAdd(&lh[b], 1);
            pay[lb[b] + r] = make_uint2(
                ((unsigned)s << 16) | ((unsigned)t << 8) | (unsigned)(key & 127),
                __float_as_uint(n));
        }
    }
}

// one block per coarse bucket: LDS counting sort of the bucket's payload;
// writes key-sorted pay2 (coalesced) + per-key CSR foffg [NK+1].
__global__ __launch_bounds__(256) void fine_sort_kernel(
    const uint2* __restrict__ pay,
    const int* __restrict__ base,
    uint2* __restrict__ pay2,
    int* __restrict__ foffg,
    int E, int NK, int NBC, int NBLK)
{
    __shared__ uint2 pay_s[CAP];     // 24 KB
    __shared__ int fcnt[CB];
    __shared__ int ssc[CB];
    __shared__ int fcur[CB];

    int b = blockIdx.x;
    int beg = base[(size_t)b * NBLK];
    int end = (b + 1 < NBC) ? base[(size_t)(b + 1) * NBLK] : E;
    int cnt = end - beg;
    int tid = threadIdx.x;

    if (tid < CB) fcnt[tid] = 0;
    __syncthreads();
    for (int j = tid; j < cnt; j += 256)
        atomicAdd(&fcnt[pay[beg + j].x & 127u], 1);
    __syncthreads();
    if (tid < CB) ssc[tid] = fcnt[tid];
    __syncthreads();
    for (int s = 1; s < CB; s <<= 1) {
        int v = 0;
        if (tid < CB && tid >= s) v = ssc[tid - s];
        __syncthreads();
        if (tid < CB) ssc[tid] += v;
        __syncthreads();
    }
    if (tid < CB) {
        int ex = ssc[tid] - fcnt[tid];
        fcur[tid] = ex;
        int key = b * CB + tid;
        if (key <= NK) foffg[key] = beg + ex;
    }
    __syncthreads();

    if (cnt <= CAP) {
        for (int j = tid; j < cnt; j += 256) {
            uint2 p = pay[beg + j];
            int r = atomicAdd(&fcur[p.x & 127u], 1);
            pay_s[r] = p;
        }
        __syncthreads();
        for (int j = tid; j < cnt; j += 256) pay2[beg + j] = pay_s[j];
    } else {
        for (int j = tid; j < cnt; j += 256) {
            uint2 p = pay[beg + j];
            int r = atomicAdd(&fcur[p.x & 127u], 1);
            pay2[beg + r] = p;
        }
    }
}

// 16-lane group per key (4 keys/wave): 4 independent edge-gather chains per
// wave, 16B row loads (8 bf16/lane), branch-free tail predication.
__global__ __launch_bounds__(256) void aggregate_g16_kernel(
    const short* __restrict__ xbf,
    const short* __restrict__ relbf,
    const uint2* __restrict__ pay2,
    const int* __restrict__ foffg,
    short* __restrict__ accbf,       // [NK,128]
    int NK, int E)
{
    int wid = (blockIdx.x * 256 + threadIdx.x) >> 6;
    int lane = threadIdx.x & 63;
    int g = lane >> 4;
    int sub = lane & 15;
    int k = wid * 4 + g;
    if (k >= NK) k = NK - 1;
    int f0 = sub << 3;

    int beg = foffg[k];
    int end = foffg[k + 1];
    int cnt = end - beg;

    int maxc = cnt;
    maxc = max(maxc, __shfl_xor(maxc, 16, 64));
    maxc = max(maxc, __shfl_xor(maxc, 32, 64));

    float a0 = 0.f, a1 = 0.f, a2 = 0.f, a3 = 0.f;
    float a4 = 0.f, a5 = 0.f, a6 = 0.f, a7 = 0.f;

    for (int bas = 0; bas < maxc; bas += 16) {
        int off = bas + sub;
        int cidx = (cnt > 0) ? min(off, cnt - 1) : 0;
        int j = min(beg + cidx, E - 1);
        uint2 p = pay2[j];
        int qmax = min(16, maxc - bas);
        for (int q = 0; q < qmax; ++q) {
            int srcl = (lane & 48) + q;
            unsigned pqx = __shfl(p.x, srcl, 64);
            unsigned pqn = __shfl(p.y, srcl, 64);
            float n = ((bas + q) < cnt) ? __uint_as_float(pqn) : 0.f;
            int s = (int)(pqx >> 16);
            int t = (int)((pqx >> 8) & 0xffu);
            uint4 xv = *reinterpret_cast<const uint4*>(xbf + (size_t)s * 128 + f0);
            uint4 rv = *reinterpret_cast<const uint4*>(relbf + (size_t)t * 128 + f0);
            a0 += bflo(xv.x) * bflo(rv.x) * n;
            a1 += bfhi(xv.x) * bfhi(rv.x) * n;
            a2 += bflo(xv.y) * bflo(rv.y) * n;
            a3 += bfhi(xv.y) * bfhi(rv.y) * n;
            a4 += bflo(xv.z) * bflo(rv.z) * n;
            a5 += bfhi(xv.z) * bfhi(rv.z) * n;
            a6 += bflo(xv.w) * bflo(rv.w) * n;
            a7 += bfhi(xv.w) * bfhi(rv.w) * n;
        }
    }
    uint4 o;
    o.x = packbf(a0, a1);
    o.y = packbf(a2, a3);
    o.z = packbf(a4, a5);
    o.w = packbf(a6, a7);
    *reinterpret_cast<uint4*>(accbf + (size_t)k * 128 + f0) = o;
}

// pack weights into bf16 MFMA B-fragment order; loop_rel folded into loop_w
__global__ __launch_bounds__(256) void wpack_kernel(
    const float* __restrict__ in_w,
    const float* __restrict__ out_w,
    const float* __restrict__ loop_w,
    const float* __restrict__ loop_rel,
    short* __restrict__ wpack)
{
    int idx = blockIdx.x * 256 + threadIdx.x;
    if (idx >= 3 * 8 * 4 * 64) return;
    int lane = idx & 63;
    int t    = (idx >> 6) & 3;
    int cblk = (idx >> 8) & 7;
    int m    = idx >> 11;
    const float* W = (m == 0) ? in_w : (m == 1) ? out_w : loop_w;
    int col = cblk * 16 + (lane & 15);
    int kb  = t * 32 + ((lane >> 4) << 3);
    short8v v;
#pragma unroll
    for (int j = 0; j < 8; ++j) {
        float w = W[(kb + j) * 128 + col];
        if (m == 2) w *= loop_rel[kb + j];
        v[j] = f2bf(w);
    }
    *reinterpret_cast<short8v*>(wpack + (size_t)idx * 8) = v;
}

// bf16 MFMA fused GEMM + bias + /3; persistent blocks (1/CU):
// 48KB weights for this col-half staged ONCE (one barrier), then a
// grid-stride loop over 128-row tiles with ZERO barriers — A-loads of the
// next tile overlap MFMAs of the current one. BN ps/pq accumulate in
// registers across tiles; single LDS reduction at the end. h stored bf16.
__global__ __launch_bounds__(512) void fused_gemm_mfma_kernel(
    const short* __restrict__ accbf,     // [2V,128]
    const short* __restrict__ xbf,       // [V,128]
    const short* __restrict__ wpack,
    const float* __restrict__ bias,
    short* __restrict__ hbf,             // [V,128] bf16 intermediate
    float* __restrict__ stats_part,      // [NGB][256]
    int V, int NRB)
{
    __shared__ short wlds[3 * 4 * 4 * 64 * 8];   // 48 KB
    __shared__ float s_red[128];                 // [0:64] sum, [64:128] sumsq

    int tid  = threadIdx.x;
    int wave = tid >> 6;                 // 0..7
    int lane = tid & 63;
    int kgrp = lane >> 4;
    int r16  = lane & 15;
    int bid  = blockIdx.x >> 1;          // 0..NGB-1
    int hh   = blockIdx.x & 1;           // column half

    if (tid < 128) s_red[tid] = 0.f;

    // stage this col-half's 3072 short8v fragments: 6 per thread
    {
        const short8v* wsv = reinterpret_cast<const short8v*>(wpack);
        short8v* wldv = reinterpret_cast<short8v*>(wlds);
#pragma unroll
        for (int i = 0; i < 6; ++i) {
            int idx = i * 512 + tid;
            int l  = idx & 63;
            int t  = (idx >> 6) & 3;
            int cb = (idx >> 8) & 3;
            int m  = idx >> 10;
            wldv[idx] = wsv[(((size_t)m * 8 + (4 * hh + cb)) * 4 + t) * 64 + l];
        }
    }
    __syncthreads();   // weights staged; s_red zeroed. NO barriers after this.

    const short8v* wldv = reinterpret_cast<const short8v*>(wlds);
    float ps[4] = {0.f, 0.f, 0.f, 0.f};
    float pq[4] = {0.f, 0.f, 0.f, 0.f};

    for (int rt = bid; rt < NRB; rt += NGB) {
        int row0 = rt * 128 + wave * 16;
        int rowl = row0 + r16;
        int rowc = min(rowl, V - 1);     // clamp (stores guarded)

        short8v af[3][4];
        {
            const short* A0 = accbf + (size_t)rowc * 128;
            const short* A1 = accbf + (size_t)(V + rowc) * 128;
            const short* A2 = xbf + (size_t)rowc * 128;
#pragma unroll
            for (int t = 0; t < 4; ++t) {
                int o = t * 32 + (kgrp << 3);
                af[0][t] = *reinterpret_cast<const short8v*>(A0 + o);
                af[1][t] = *reinterpret_cast<const short8v*>(A1 + o);
                af[2][t] = *reinterpret_cast<const short8v*>(A2 + o);
            }
        }

        float4v c[4];
#pragma unroll
        for (int b = 0; b < 4; ++b) c[b] = (float4v)(0.f);

#pragma unroll
        for (int m = 0; m < 3; ++m)
#pragma unroll
            for (int t = 0; t < 4; ++t) {
#pragma unroll
                for (int b = 0; b < 4; ++b) {
                    short8v bf_ = wldv[(((m * 4 + b) * 4) + t) * 64 + lane];
                    c[b] = __builtin_amdgcn_mfma_f32_16x16x32_bf16(af[m][t], bf_, c[b], 0, 0, 0);
                }
            }

        // epilogue: C/D layout col=lane&15, row=(lane>>4)*4+r  [m89]
#pragma unroll
        for (int b = 0; b < 4; ++b) {
            int col = hh * 64 + b * 16 + r16;
            float bv = bias[col];
#pragma unroll
            for (int r = 0; r < 4; ++r) {
                int row = row0 + kgrp * 4 + r;
                if (row < V) {
                    float v = c[b][r] * (1.f / 3.f) + bv;
                    hbf[(size_t)row * 128 + col] = f2bf(v);
                    ps[b] += v;
                    pq[b] += v * v;
                }
            }
        }
    }

    // single stats reduction
#pragma unroll
    for (int b = 0; b < 4; ++b) {
        int cl = b * 16 + r16;
        atomicAdd(&s_red[cl], ps[b]);
        atomicAdd(&s_red[64 + cl], pq[b]);
    }
    __syncthreads();
    if (tid < 64)
        stats_part[(size_t)bid * 256 + hh * 64 + tid] = s_red[tid];
    else if (tid < 128)
        stats_part[(size_t)bid * 256 + 128 + hh * 64 + (tid - 64)] = s_red[tid];
}

// BN reduce stage 1: 64 blocks, each sums a strided subset of NB partials
__global__ __launch_bounds__(256) void bn_reduce1_kernel(
    const float* __restrict__ stats_part, float* __restrict__ stage, int NB)
{
    int col = threadIdx.x;
    float s = 0.f;
    for (int i = blockIdx.x; i < NB; i += RED1)
        s += stats_part[(size_t)i * 256 + col];
    stage[(size_t)blockIdx.x * 256 + col] = s;
}

// BN reduce stage 2: one block over fixed RED1 partials, fully unrolled
__global__ __launch_bounds__(256) void bn_reduce2_kernel(
    const float* __restrict__ stage, float* __restrict__ stats)
{
    int col = threadIdx.x;
    float s0 = 0.f, s1 = 0.f, s2 = 0.f, s3 = 0.f;
#pragma unroll
    for (int i = 0; i < RED1; i += 4) {
        s0 += stage[(size_t)(i + 0) * 256 + col];
        s1 += stage[(size_t)(i + 1) * 256 + col];
        s2 += stage[(size_t)(i + 2) * 256 + col];
        s3 += stage[(size_t)(i + 3) * 256 + col];
    }
    stats[col] = (s0 + s1) + (s2 + s3);
}

// vectorized BN apply + ReLU: bf16 in (uint2 = 4 bf16), f32 out (float4)
__global__ __launch_bounds__(256) void bn_apply_kernel(
    const short* __restrict__ hbf,
    float* __restrict__ hout,
    const float* __restrict__ stats,
    const float* __restrict__ gamma,
    const float* __restrict__ beta,
    int V)
{
    int c4   = (threadIdx.x & 31) << 2;
    int rsub = threadIdx.x >> 5;
    float inv_v = 1.f / (float)V;
    float sc[4], sh[4];
#pragma unroll
    for (int j = 0; j < 4; ++j) {
        int col = c4 + j;
        float mean = stats[col] * inv_v;
        float var  = stats[128 + col] * inv_v - mean * mean;
        float s = rsqrtf(var + 1e-5f) * gamma[col];
        sc[j] = s;
        sh[j] = beta[col] - mean * s;
    }
    for (int row = blockIdx.x * 8 + rsub; row < V; row += gridDim.x * 8) {
        uint2 u = *reinterpret_cast<const uint2*>(hbf + (size_t)row * 128 + c4);
        float4 v;
        v.x = fmaxf(bflo(u.x) * sc[0] + sh[0], 0.f);
        v.y = fmaxf(bfhi(u.x) * sc[1] + sh[1], 0.f);
        v.z = fmaxf(bflo(u.y) * sc[2] + sh[2], 0.f);
        v.w = fmaxf(bfhi(u.y) * sc[3] + sh[3], 0.f);
        *reinterpret_cast<float4*>(hout + (size_t)row * 128 + c4) = v;
    }
}

__global__ __launch_bounds__(256) void rel_gemm_kernel(
    const float* __restrict__ rel,
    const float* __restrict__ w_rel,
    float* __restrict__ out_rel,
    int R)
{
    int col = threadIdx.x & 127;
    int row = blockIdx.x * 2 + (threadIdx.x >> 7);
    if (row >= R) return;
    float acc = 0.f;
    for (int k = 0; k < 128; ++k)
        acc += rel[row * 128 + k] * w_rel[k * 128 + col];
    out_rel[row * 128 + col] = acc;
}

extern "C" void kernel_launch(void* const* d_in, const int* in_sizes, int n_in,
                              void* d_out, int out_size, void* d_ws, size_t ws_size,
                              hipStream_t stream)
{
    const float* x         = (const float*)d_in[0];
    const float* rel_repr  = (const float*)d_in[1];
    const float* edge_norm = (const float*)d_in[2];
    const float* in_w      = (const float*)d_in[3];
    const float* out_w     = (const float*)d_in[4];
    const float* loop_w    = (const float*)d_in[5];
    const float* w_rel     = (const float*)d_in[6];
    const float* loop_rel  = (const float*)d_in[7];
    const float* bias      = (const float*)d_in[8];
    const float* bn_gamma  = (const float*)d_in[9];
    const float* bn_beta   = (const float*)d_in[10];
    const int* edge_type   = (const int*)d_in[11];
    const int* src         = (const int*)d_in[12];
    const int* dst         = (const int*)d_in[13];

    const int V = in_sizes[0] / 128;     // 50000
    const int E = in_sizes[2];           // 800000
    const int R = in_sizes[1] / 128;     // 200
    const int NK = 2 * V;                // keys: [dst(in) ; dst(out)]
    const int NBC = (NK + CB - 1) / CB;              // coarse buckets (782)
    const int NBLK = (E + CHUNK - 1) / CHUNK;        // hist/rank blocks (196)
    const int CN = NBC * NBLK;                       // scan length
    const int NB2 = (CN + SCAN_BLOCK - 1) / SCAN_BLOCK;
    const int NRB = (V + 127) / 128;                 // GEMM row tiles (391)

    float* hout    = (float*)d_out;              // [V,128]
    float* out_rel = hout + (size_t)V * 128;     // [R,128]

    // workspace layout
    char* wp_ = (char*)d_ws;
    short* accbf    = (short*)wp_;  wp_ += (size_t)NK * 128 * sizeof(short);
    short* xbf      = (short*)wp_;  wp_ += (size_t)V * 128 * sizeof(short);
    short* relbf    = (short*)wp_;  wp_ += (size_t)R * 128 * sizeof(short);
    short* hbf      = (short*)wp_;  wp_ += (size_t)V * 128 * sizeof(short);
    short* wpack    = (short*)wp_;  wp_ += (size_t)3 * 8 * 4 * 64 * 8 * sizeof(short);
    float* stats    = (float*)wp_;  wp_ += 256 * sizeof(float);
    float* stats_pt = (float*)wp_;  wp_ += (size_t)NGB * 256 * sizeof(float);
    float* stage    = (float*)wp_;  wp_ += (size_t)RED1 * 256 * sizeof(float);
    int*   counts   = (int*)wp_;    wp_ += (size_t)CN * sizeof(int);   // block-major
    int*   basep    = (int*)wp_;    wp_ += (size_t)CN * sizeof(int);   // bucket-major
    int*   partials = (int*)wp_;    wp_ += 1024 * sizeof(int);
    int*   foffg    = (int*)wp_;    wp_ += ((size_t)NK + 2) * sizeof(int);
    wp_ = (char*)(((uintptr_t)wp_ + 15) & ~(uintptr_t)15);
    uint2* pay      = (uint2*)wp_;  wp_ += (size_t)E * sizeof(uint2);
    uint2* pay2     = (uint2*)wp_;

    // NOTE: no memset needed — every consumed workspace buffer is fully
    // written each call.

    {
        size_t total = ((size_t)(V + R) * 128) / 8;
        xcast_kernel<<<(int)((total + 255) / 256), 256, 0, stream>>>(
            x, rel_repr, xbf, relbf, V, R);
    }
    wpack_kernel<<<(3 * 8 * 4 * 64 + 255) / 256, 256, 0, stream>>>(
        in_w, out_w, loop_w, loop_rel, wpack);

    hist_coarse_kernel<<<NBLK, 256, 0, stream>>>(dst, counts, E, V, NBC);
    scan_partial_t_kernel<<<NB2, SCAN_BLOCK, 0, stream>>>(counts, partials, CN, NBC, NBLK);
    scan_top_kernel<<<1, 1024, 0, stream>>>(partials, NB2);
    scan_final_t_kernel<<<NB2, SCAN_BLOCK, 0, stream>>>(counts, partials, basep, CN, NBC, NBLK);
    rank_coarse_kernel<<<NBLK, 256, 0, stream>>>(
        dst, src, edge_type, edge_norm, basep, pay, E, V, NBC, NBLK);
    fine_sort_kernel<<<NBC, 256, 0, stream>>>(
        pay, basep, pay2, foffg, E, NK, NBC, NBLK);

    {
        int waves = (NK + 3) / 4;                        // 25000
        int blocks = (waves * 64 + 255) / 256;           // 6250
        aggregate_g16_kernel<<<blocks, 256, 0, stream>>>(
            xbf, relbf, pay2, foffg, accbf, NK, E);
    }

    fused_gemm_mfma_kernel<<<NGB * 2, 512, 0, stream>>>(
        accbf, xbf, wpack, bias, hbf, stats_pt, V, NRB);

    bn_reduce1_kernel<<<RED1, 256, 0, stream>>>(stats_pt, stage, NGB);
    bn_reduce2_kernel<<<1, 256, 0, stream>>>(stage, stats);
    bn_apply_kernel<<<1024, 256, 0, stream>>>(hbf, hout, stats, bn_gamma, bn_beta, V);
    rel_gemm_kernel<<<(R + 1) / 2, 256, 0, stream>>>(rel_repr, w_rel, out_rel, R);
}

// Round 23
// 114.407 us; speedup vs baseline: 1.2692x; 1.0883x over previous
//
#include <hip/hip_runtime.h>
#include <hip/hip_bf16.h>

// ---------------------------------------------------------------------------
// CompGCN layer:
//   bf16 data plane; coarse-bucket (128 keys) counting sort (low write amp,
//   512-thread hist/rank: halve per-block serial iterations); 2-kernel scan
//   (per-block prefix reduce replaces scan_top); per-bucket LDS fine sort
//   (512 threads); 16-lane-group aggregation; persistent-block bf16-MFMA
//   fused GEMM (1 block/CU, weights staged once, zero-barrier tile loop);
//   BN reduce stage1 + fused {stats-finalize + BN apply + ReLU + rel GEMM}.
// ---------------------------------------------------------------------------

#define SCAN_BLOCK 256
#define CB 128               // keys per coarse bucket
#define CHUNK 4096           // edges per hist/rank block
#define NBC_MAX 800          // >= ceil(2V/CB) = 782
#define CAP 3072             // LDS staging cap per bucket (lambda=1024, 64 sigma)
#define RED1 64              // stage-1 reduce blocks (fixed)
#define NGB 128              // GEMM row-group blocks per column half

typedef __attribute__((ext_vector_type(8))) short short8v;   // 8 bf16
typedef __attribute__((ext_vector_type(4))) float float4v;   // MFMA C/D

__device__ inline short f2bf(float f) {
    union { float f; unsigned u; } c; c.f = f;
    unsigned u = c.u;
    return (short)((u + 0x7fffu + ((u >> 16) & 1u)) >> 16);  // RNE
}
__device__ inline unsigned packbf(float a, float b) {
    return (unsigned)(unsigned short)f2bf(a) |
           ((unsigned)(unsigned short)f2bf(b) << 16);
}
__device__ inline float bflo(unsigned u) { return __uint_as_float(u << 16); }
__device__ inline float bfhi(unsigned u) { return __uint_as_float(u & 0xffff0000u); }

// cast x [V,128] and rel [R,128] to bf16, 8 elems/thread
__global__ __launch_bounds__(256) void xcast_kernel(
    const float* __restrict__ x, const float* __restrict__ rel,
    short* __restrict__ xbf, short* __restrict__ relbf, int V, int R)
{
    size_t i = ((size_t)blockIdx.x * 256 + threadIdx.x) * 8;
    size_t nx = (size_t)V * 128;
    size_t total = nx + (size_t)R * 128;
    if (i >= total) return;
    const float* sp; short* dp; size_t k;
    if (i < nx) { sp = x; dp = xbf; k = i; }
    else        { sp = rel; dp = relbf; k = i - nx; }
    float4 v0 = *reinterpret_cast<const float4*>(sp + k);
    float4 v1 = *reinterpret_cast<const float4*>(sp + k + 4);
    short8v o;
    o[0] = f2bf(v0.x); o[1] = f2bf(v0.y); o[2] = f2bf(v0.z); o[3] = f2bf(v0.w);
    o[4] = f2bf(v1.x); o[5] = f2bf(v1.y); o[6] = f2bf(v1.z); o[7] = f2bf(v1.w);
    *reinterpret_cast<short8v*>(dp + k) = o;
}

// per-block LDS histogram over coarse buckets; counts stored BLOCK-MAJOR.
// 512 threads: 8 serial iterations per block instead of 16 (196 blocks
// underfill the machine -> per-block parallelism is the lever).
__global__ __launch_bounds__(512) void hist_coarse_kernel(
    const int* __restrict__ dst, int* __restrict__ counts,
    int E, int V, int NBC)
{
    __shared__ int lh[NBC_MAX];
    for (int i = threadIdx.x; i < NBC; i += 512) lh[i] = 0;
    __syncthreads();
    int half = E >> 1;
    int e0 = blockIdx.x * CHUNK;
    for (int i = 0; i < CHUNK / 512; ++i) {
        int e = e0 + i * 512 + threadIdx.x;
        if (e < E) {
            int key = dst[e] + (e < half ? 0 : V);
            atomicAdd(&lh[key >> 7], 1);
        }
    }
    __syncthreads();
    for (int i = threadIdx.x; i < NBC; i += 512)
        counts[(size_t)blockIdx.x * NBC + i] = lh[i];
}

// scan phase 1, TRANSPOSED read: logical l = bucket*NBLK + blk.
// Writes RAW per-block sums (no separate top-scan kernel anymore).
__global__ __launch_bounds__(SCAN_BLOCK) void scan_partial_t_kernel(
    const int* __restrict__ cnt_bm, int* __restrict__ partials,
    int CN, int NBC, int NBLK)
{
    __shared__ int red[SCAN_BLOCK];
    int l = blockIdx.x * SCAN_BLOCK + threadIdx.x;
    int v = 0;
    if (l < CN) {
        int bu = l / NBLK, bl = l - bu * NBLK;
        v = cnt_bm[(size_t)bl * NBC + bu];
    }
    red[threadIdx.x] = v;
    __syncthreads();
    for (int s = SCAN_BLOCK / 2; s > 0; s >>= 1) {
        if (threadIdx.x < s) red[threadIdx.x] += red[threadIdx.x + s];
        __syncthreads();
    }
    if (threadIdx.x == 0) partials[blockIdx.x] = red[0];
}

// scan phase 2 (fused): block bid reduces partials[0..bid) itself (<=3
// strided iterations), then does the local Hillis-Steele scan.
__global__ __launch_bounds__(SCAN_BLOCK) void scan_final_t_kernel(
    const int* __restrict__ cnt_bm, const int* __restrict__ partials,
    int* __restrict__ base, int CN, int NBC, int NBLK)
{
    __shared__ int sh[SCAN_BLOCK];
    __shared__ int pref_s;
    int t = threadIdx.x;
    int bid = blockIdx.x;

    // exclusive prefix of raw partials[0..bid)
    int acc = 0;
    for (int i = t; i < bid; i += SCAN_BLOCK) acc += partials[i];
    sh[t] = acc;
    __syncthreads();
    for (int s = SCAN_BLOCK / 2; s > 0; s >>= 1) {
        if (t < s) sh[t] += sh[t + s];
        __syncthreads();
    }
    if (t == 0) pref_s = sh[0];
    __syncthreads();
    int pref = pref_s;
    __syncthreads();   // sh[] reuse

    int l = bid * SCAN_BLOCK + t;
    int v = 0;
    if (l < CN) {
        int bu = l / NBLK, bl = l - bu * NBLK;
        v = cnt_bm[(size_t)bl * NBC + bu];
    }
    sh[t] = v;
    __syncthreads();
    for (int s = 1; s < SCAN_BLOCK; s <<= 1) {
        int u = (t >= s) ? sh[t - s] : 0;
        __syncthreads();
        sh[t] += u;
        __syncthreads();
    }
    if (l < CN) base[l] = pref + sh[t] - v;
}

// scatter payload; per-(bucket,block) runs contiguous, written from one CU.
// payload: (src<<16 | type<<8 | key&127, norm-bits). 512 threads.
__global__ __launch_bounds__(512) void rank_coarse_kernel(
    const int* __restrict__ dst,
    const int* __restrict__ src,
    const int* __restrict__ edge_type,
    const float* __restrict__ edge_norm,
    const int* __restrict__ base,
    uint2* __restrict__ pay,
    int E, int V, int NBC, int NBLK)
{
    __shared__ int lh[NBC_MAX];
    __shared__ int lb[NBC_MAX];
    for (int i = threadIdx.x; i < NBC; i += 512) {
        lh[i] = 0;
        lb[i] = base[(size_t)i * NBLK + blockIdx.x];
    }
    __syncthreads();
    int half = E >> 1;
    int e0 = blockIdx.x * CHUNK;
    for (int i = 0; i < CHUNK / 512; ++i) {
        int e = e0 + i * 512 + threadIdx.x;
        if (e < E) {
            int d = dst[e], s = src[e], t = edge_type[e];
            float n = edge_norm[e];
            int key = d + (e < half ? 0 : V);
            int b = key >> 7;
            int r = atomicAdd(&lh[b], 1);
            pay[lb[b] + r] = make_uint2(
                ((unsigned)s << 16) | ((unsigned)t << 8) | (unsigned)(key & 127),
                __float_as_uint(n));
        }
    }
}

// one block per coarse bucket: LDS counting sort of the bucket's payload;
// writes key-sorted pay2 (coalesced) + per-key CSR foffg [NK+1]. 512 threads.
__global__ __launch_bounds__(512) void fine_sort_kernel(
    const uint2* __restrict__ pay,
    const int* __restrict__ base,
    uint2* __restrict__ pay2,
    int* __restrict__ foffg,
    int E, int NK, int NBC, int NBLK)
{
    __shared__ uint2 pay_s[CAP];     // 24 KB
    __shared__ int fcnt[CB];
    __shared__ int ssc[CB];
    __shared__ int fcur[CB];

    int b = blockIdx.x;
    int beg = base[(size_t)b * NBLK];
    int end = (b + 1 < NBC) ? base[(size_t)(b + 1) * NBLK] : E;
    int cnt = end - beg;
    int tid = threadIdx.x;

    if (tid < CB) fcnt[tid] = 0;
    __syncthreads();
    for (int j = tid; j < cnt; j += 512)
        atomicAdd(&fcnt[pay[beg + j].x & 127u], 1);
    __syncthreads();
    if (tid < CB) ssc[tid] = fcnt[tid];
    __syncthreads();
    for (int s = 1; s < CB; s <<= 1) {
        int v = 0;
        if (tid < CB && tid >= s) v = ssc[tid - s];
        __syncthreads();
        if (tid < CB) ssc[tid] += v;
        __syncthreads();
    }
    if (tid < CB) {
        int ex = ssc[tid] - fcnt[tid];
        fcur[tid] = ex;
        int key = b * CB + tid;
        if (key <= NK) foffg[key] = beg + ex;
    }
    __syncthreads();

    if (cnt <= CAP) {
        for (int j = tid; j < cnt; j += 512) {
            uint2 p = pay[beg + j];
            int r = atomicAdd(&fcur[p.x & 127u], 1);
            pay_s[r] = p;
        }
        __syncthreads();
        for (int j = tid; j < cnt; j += 512) pay2[beg + j] = pay_s[j];
    } else {
        for (int j = tid; j < cnt; j += 512) {
            uint2 p = pay[beg + j];
            int r = atomicAdd(&fcur[p.x & 127u], 1);
            pay2[beg + r] = p;
        }
    }
}

// 16-lane group per key (4 keys/wave): 4 independent edge-gather chains per
// wave, 16B row loads (8 bf16/lane), branch-free tail predication.
__global__ __launch_bounds__(256) void aggregate_g16_kernel(
    const short* __restrict__ xbf,
    const short* __restrict__ relbf,
    const uint2* __restrict__ pay2,
    const int* __restrict__ foffg,
    short* __restrict__ accbf,       // [NK,128]
    int NK, int E)
{
    int wid = (blockIdx.x * 256 + threadIdx.x) >> 6;
    int lane = threadIdx.x & 63;
    int g = lane >> 4;
    int sub = lane & 15;
    int k = wid * 4 + g;
    if (k >= NK) k = NK - 1;
    int f0 = sub << 3;

    int beg = foffg[k];
    int end = foffg[k + 1];
    int cnt = end - beg;

    int maxc = cnt;
    maxc = max(maxc, __shfl_xor(maxc, 16, 64));
    maxc = max(maxc, __shfl_xor(maxc, 32, 64));

    float a0 = 0.f, a1 = 0.f, a2 = 0.f, a3 = 0.f;
    float a4 = 0.f, a5 = 0.f, a6 = 0.f, a7 = 0.f;

    for (int bas = 0; bas < maxc; bas += 16) {
        int off = bas + sub;
        int cidx = (cnt > 0) ? min(off, cnt - 1) : 0;
        int j = min(beg + cidx, E - 1);
        uint2 p = pay2[j];
        int qmax = min(16, maxc - bas);
        for (int q = 0; q < qmax; ++q) {
            int srcl = (lane & 48) + q;
            unsigned pqx = __shfl(p.x, srcl, 64);
            unsigned pqn = __shfl(p.y, srcl, 64);
            float n = ((bas + q) < cnt) ? __uint_as_float(pqn) : 0.f;
            int s = (int)(pqx >> 16);
            int t = (int)((pqx >> 8) & 0xffu);
            uint4 xv = *reinterpret_cast<const uint4*>(xbf + (size_t)s * 128 + f0);
            uint4 rv = *reinterpret_cast<const uint4*>(relbf + (size_t)t * 128 + f0);
            a0 += bflo(xv.x) * bflo(rv.x) * n;
            a1 += bfhi(xv.x) * bfhi(rv.x) * n;
            a2 += bflo(xv.y) * bflo(rv.y) * n;
            a3 += bfhi(xv.y) * bfhi(rv.y) * n;
            a4 += bflo(xv.z) * bflo(rv.z) * n;
            a5 += bfhi(xv.z) * bfhi(rv.z) * n;
            a6 += bflo(xv.w) * bflo(rv.w) * n;
            a7 += bfhi(xv.w) * bfhi(rv.w) * n;
        }
    }
    uint4 o;
    o.x = packbf(a0, a1);
    o.y = packbf(a2, a3);
    o.z = packbf(a4, a5);
    o.w = packbf(a6, a7);
    *reinterpret_cast<uint4*>(accbf + (size_t)k * 128 + f0) = o;
}

// pack weights into bf16 MFMA B-fragment order; loop_rel folded into loop_w
__global__ __launch_bounds__(256) void wpack_kernel(
    const float* __restrict__ in_w,
    const float* __restrict__ out_w,
    const float* __restrict__ loop_w,
    const float* __restrict__ loop_rel,
    short* __restrict__ wpack)
{
    int idx = blockIdx.x * 256 + threadIdx.x;
    if (idx >= 3 * 8 * 4 * 64) return;
    int lane = idx & 63;
    int t    = (idx >> 6) & 3;
    int cblk = (idx >> 8) & 7;
    int m    = idx >> 11;
    const float* W = (m == 0) ? in_w : (m == 1) ? out_w : loop_w;
    int col = cblk * 16 + (lane & 15);
    int kb  = t * 32 + ((lane >> 4) << 3);
    short8v v;
#pragma unroll
    for (int j = 0; j < 8; ++j) {
        float w = W[(kb + j) * 128 + col];
        if (m == 2) w *= loop_rel[kb + j];
        v[j] = f2bf(w);
    }
    *reinterpret_cast<short8v*>(wpack + (size_t)idx * 8) = v;
}

// bf16 MFMA fused GEMM + bias + /3; persistent blocks (1/CU):
// 48KB weights staged ONCE, zero-barrier tile loop (round-22 winner).
__global__ __launch_bounds__(512) void fused_gemm_mfma_kernel(
    const short* __restrict__ accbf,     // [2V,128]
    const short* __restrict__ xbf,       // [V,128]
    const short* __restrict__ wpack,
    const float* __restrict__ bias,
    short* __restrict__ hbf,             // [V,128] bf16 intermediate
    float* __restrict__ stats_part,      // [NGB][256]
    int V, int NRB)
{
    __shared__ short wlds[3 * 4 * 4 * 64 * 8];   // 48 KB
    __shared__ float s_red[128];                 // [0:64] sum, [64:128] sumsq

    int tid  = threadIdx.x;
    int wave = tid >> 6;
    int lane = tid & 63;
    int kgrp = lane >> 4;
    int r16  = lane & 15;
    int bid  = blockIdx.x >> 1;
    int hh   = blockIdx.x & 1;

    if (tid < 128) s_red[tid] = 0.f;

    {
        const short8v* wsv = reinterpret_cast<const short8v*>(wpack);
        short8v* wldv = reinterpret_cast<short8v*>(wlds);
#pragma unroll
        for (int i = 0; i < 6; ++i) {
            int idx = i * 512 + tid;
            int l  = idx & 63;
            int t  = (idx >> 6) & 3;
            int cb = (idx >> 8) & 3;
            int m  = idx >> 10;
            wldv[idx] = wsv[(((size_t)m * 8 + (4 * hh + cb)) * 4 + t) * 64 + l];
        }
    }
    __syncthreads();   // weights staged; s_red zeroed. NO barriers after this.

    const short8v* wldv = reinterpret_cast<const short8v*>(wlds);
    float ps[4] = {0.f, 0.f, 0.f, 0.f};
    float pq[4] = {0.f, 0.f, 0.f, 0.f};

    for (int rt = bid; rt < NRB; rt += NGB) {
        int row0 = rt * 128 + wave * 16;
        int rowl = row0 + r16;
        int rowc = min(rowl, V - 1);

        short8v af[3][4];
        {
            const short* A0 = accbf + (size_t)rowc * 128;
            const short* A1 = accbf + (size_t)(V + rowc) * 128;
            const short* A2 = xbf + (size_t)rowc * 128;
#pragma unroll
            for (int t = 0; t < 4; ++t) {
                int o = t * 32 + (kgrp << 3);
                af[0][t] = *reinterpret_cast<const short8v*>(A0 + o);
                af[1][t] = *reinterpret_cast<const short8v*>(A1 + o);
                af[2][t] = *reinterpret_cast<const short8v*>(A2 + o);
            }
        }

        float4v c[4];
#pragma unroll
        for (int b = 0; b < 4; ++b) c[b] = (float4v)(0.f);

#pragma unroll
        for (int m = 0; m < 3; ++m)
#pragma unroll
            for (int t = 0; t < 4; ++t) {
#pragma unroll
                for (int b = 0; b < 4; ++b) {
                    short8v bf_ = wldv[(((m * 4 + b) * 4) + t) * 64 + lane];
                    c[b] = __builtin_amdgcn_mfma_f32_16x16x32_bf16(af[m][t], bf_, c[b], 0, 0, 0);
                }
            }

        // epilogue: C/D layout col=lane&15, row=(lane>>4)*4+r  [m89]
#pragma unroll
        for (int b = 0; b < 4; ++b) {
            int col = hh * 64 + b * 16 + r16;
            float bv = bias[col];
#pragma unroll
            for (int r = 0; r < 4; ++r) {
                int row = row0 + kgrp * 4 + r;
                if (row < V) {
                    float v = c[b][r] * (1.f / 3.f) + bv;
                    hbf[(size_t)row * 128 + col] = f2bf(v);
                    ps[b] += v;
                    pq[b] += v * v;
                }
            }
        }
    }

#pragma unroll
    for (int b = 0; b < 4; ++b) {
        int cl = b * 16 + r16;
        atomicAdd(&s_red[cl], ps[b]);
        atomicAdd(&s_red[64 + cl], pq[b]);
    }
    __syncthreads();
    if (tid < 64)
        stats_part[(size_t)bid * 256 + hh * 64 + tid] = s_red[tid];
    else if (tid < 128)
        stats_part[(size_t)bid * 256 + 128 + hh * 64 + (tid - 64)] = s_red[tid];
}

// BN reduce stage 1: 64 blocks, each sums a strided subset of NB partials
__global__ __launch_bounds__(256) void bn_reduce1_kernel(
    const float* __restrict__ stats_part, float* __restrict__ stage, int NB)
{
    int col = threadIdx.x;
    float s = 0.f;
    for (int i = blockIdx.x; i < NB; i += RED1)
        s += stats_part[(size_t)i * 256 + col];
    stage[(size_t)blockIdx.x * 256 + col] = s;
}

// fused: per-block stats finalize (reduce stage[64][256] in LDS) + BN apply
// + ReLU (bf16 in, f32 out); blocks >= NBA compute out_rel = rel @ w_rel.
__global__ __launch_bounds__(256) void bn_apply_fused_kernel(
    const short* __restrict__ hbf,
    float* __restrict__ hout,
    const float* __restrict__ stage,
    const float* __restrict__ gamma,
    const float* __restrict__ beta,
    int V, int NBA,
    const float* __restrict__ rel,
    const float* __restrict__ w_rel,
    float* __restrict__ out_rel,
    int R)
{
    int tid = threadIdx.x;
    if ((int)blockIdx.x >= NBA) {
        // rel GEMM tail blocks
        int rb = blockIdx.x - NBA;
        int col = tid & 127;
        int row = rb * 2 + (tid >> 7);
        if (row >= R) return;
        float acc = 0.f;
        for (int k = 0; k < 128; ++k)
            acc += rel[row * 128 + k] * w_rel[k * 128 + col];
        out_rel[row * 128 + col] = acc;
        return;
    }

    __shared__ float st[256];
    {
        float s0 = 0.f, s1 = 0.f, s2 = 0.f, s3 = 0.f;
#pragma unroll
        for (int i = 0; i < RED1; i += 4) {
            s0 += stage[(size_t)(i + 0) * 256 + tid];
            s1 += stage[(size_t)(i + 1) * 256 + tid];
            s2 += stage[(size_t)(i + 2) * 256 + tid];
            s3 += stage[(size_t)(i + 3) * 256 + tid];
        }
        st[tid] = (s0 + s1) + (s2 + s3);
    }
    __syncthreads();

    int c4   = (tid & 31) << 2;
    int rsub = tid >> 5;
    float inv_v = 1.f / (float)V;
    float sc[4], sh[4];
#pragma unroll
    for (int j = 0; j < 4; ++j) {
        int col = c4 + j;
        float mean = st[col] * inv_v;
        float var  = st[128 + col] * inv_v - mean * mean;
        float s = rsqrtf(var + 1e-5f) * gamma[col];
        sc[j] = s;
        sh[j] = beta[col] - mean * s;
    }
    for (int row = blockIdx.x * 8 + rsub; row < V; row += NBA * 8) {
        uint2 u = *reinterpret_cast<const uint2*>(hbf + (size_t)row * 128 + c4);
        float4 v;
        v.x = fmaxf(bflo(u.x) * sc[0] + sh[0], 0.f);
        v.y = fmaxf(bfhi(u.x) * sc[1] + sh[1], 0.f);
        v.z = fmaxf(bflo(u.y) * sc[2] + sh[2], 0.f);
        v.w = fmaxf(bfhi(u.y) * sc[3] + sh[3], 0.f);
        *reinterpret_cast<float4*>(hout + (size_t)row * 128 + c4) = v;
    }
}

extern "C" void kernel_launch(void* const* d_in, const int* in_sizes, int n_in,
                              void* d_out, int out_size, void* d_ws, size_t ws_size,
                              hipStream_t stream)
{
    const float* x         = (const float*)d_in[0];
    const float* rel_repr  = (const float*)d_in[1];
    const float* edge_norm = (const float*)d_in[2];
    const float* in_w      = (const float*)d_in[3];
    const float* out_w     = (const float*)d_in[4];
    const float* loop_w    = (const float*)d_in[5];
    const float* w_rel     = (const float*)d_in[6];
    const float* loop_rel  = (const float*)d_in[7];
    const float* bias      = (const float*)d_in[8];
    const float* bn_gamma  = (const float*)d_in[9];
    const float* bn_beta   = (const float*)d_in[10];
    const int* edge_type   = (const int*)d_in[11];
    const int* src         = (const int*)d_in[12];
    const int* dst         = (const int*)d_in[13];

    const int V = in_sizes[0] / 128;     // 50000
    const int E = in_sizes[2];           // 800000
    const int R = in_sizes[1] / 128;     // 200
    const int NK = 2 * V;                // keys: [dst(in) ; dst(out)]
    const int NBC = (NK + CB - 1) / CB;              // coarse buckets (782)
    const int NBLK = (E + CHUNK - 1) / CHUNK;        // hist/rank blocks (196)
    const int CN = NBC * NBLK;                       // scan length
    const int NB2 = (CN + SCAN_BLOCK - 1) / SCAN_BLOCK;
    const int NRB = (V + 127) / 128;                 // GEMM row tiles (391)
    const int NBA = 256;                             // bn_apply blocks

    float* hout    = (float*)d_out;              // [V,128]
    float* out_rel = hout + (size_t)V * 128;     // [R,128]

    // workspace layout
    char* wp_ = (char*)d_ws;
    short* accbf    = (short*)wp_;  wp_ += (size_t)NK * 128 * sizeof(short);
    short* xbf      = (short*)wp_;  wp_ += (size_t)V * 128 * sizeof(short);
    short* relbf    = (short*)wp_;  wp_ += (size_t)R * 128 * sizeof(short);
    short* hbf      = (short*)wp_;  wp_ += (size_t)V * 128 * sizeof(short);
    short* wpack    = (short*)wp_;  wp_ += (size_t)3 * 8 * 4 * 64 * 8 * sizeof(short);
    float* stats_pt = (float*)wp_;  wp_ += (size_t)NGB * 256 * sizeof(float);
    float* stage    = (float*)wp_;  wp_ += (size_t)RED1 * 256 * sizeof(float);
    int*   counts   = (int*)wp_;    wp_ += (size_t)CN * sizeof(int);   // block-major
    int*   basep    = (int*)wp_;    wp_ += (size_t)CN * sizeof(int);   // bucket-major
    int*   partials = (int*)wp_;    wp_ += 1024 * sizeof(int);
    int*   foffg    = (int*)wp_;    wp_ += ((size_t)NK + 2) * sizeof(int);
    wp_ = (char*)(((uintptr_t)wp_ + 15) & ~(uintptr_t)15);
    uint2* pay      = (uint2*)wp_;  wp_ += (size_t)E * sizeof(uint2);
    uint2* pay2     = (uint2*)wp_;

    // NOTE: no memset needed — every consumed workspace buffer is fully
    // written each call.

    {
        size_t total = ((size_t)(V + R) * 128) / 8;
        xcast_kernel<<<(int)((total + 255) / 256), 256, 0, stream>>>(
            x, rel_repr, xbf, relbf, V, R);
    }
    wpack_kernel<<<(3 * 8 * 4 * 64 + 255) / 256, 256, 0, stream>>>(
        in_w, out_w, loop_w, loop_rel, wpack);

    hist_coarse_kernel<<<NBLK, 512, 0, stream>>>(dst, counts, E, V, NBC);
    scan_partial_t_kernel<<<NB2, SCAN_BLOCK, 0, stream>>>(counts, partials, CN, NBC, NBLK);
    scan_final_t_kernel<<<NB2, SCAN_BLOCK, 0, stream>>>(counts, partials, basep, CN, NBC, NBLK);
    rank_coarse_kernel<<<NBLK, 512, 0, stream>>>(
        dst, src, edge_type, edge_norm, basep, pay, E, V, NBC, NBLK);
    fine_sort_kernel<<<NBC, 512, 0, stream>>>(
        pay, basep, pay2, foffg, E, NK, NBC, NBLK);

    {
        int waves = (NK + 3) / 4;                        // 25000
        int blocks = (waves * 64 + 255) / 256;           // 6250
        aggregate_g16_kernel<<<blocks, 256, 0, stream>>>(
            xbf, relbf, pay2, foffg, accbf, NK, E);
    }

    fused_gemm_mfma_kernel<<<NGB * 2, 512, 0, stream>>>(
        accbf, xbf, wpack, bias, hbf, stats_pt, V, NRB);

    bn_reduce1_kernel<<<RED1, 256, 0, stream>>>(stats_pt, stage, NGB);
    bn_apply_fused_kernel<<<NBA + (R + 1) / 2, 256, 0, stream>>>(
        hbf, hout, stage, bn_gamma, bn_beta, V, NBA,
        rel_repr, w_rel, out_rel, R);
}

// Round 24
// 111.938 us; speedup vs baseline: 1.2972x; 1.0221x over previous
//
#include <hip/hip_runtime.h>
#include <hip/hip_bf16.h>

// ---------------------------------------------------------------------------
// CompGCN layer:
//   fused prep (xcast + wpack + hist: independent -> one dispatch);
//   coarse-bucket counting sort (low write amp, 512-thread rank);
//   per-bucket LDS fine sort (512 threads) -> key-sorted payload + CSR;
//   16-lane-group aggregation; persistent-block bf16-MFMA fused GEMM
//   (1 block/CU, weights staged once, zero-barrier tile loop); BN reduce
//   stage1 + fused {stats-finalize + BN apply + ReLU + rel GEMM}.
// ---------------------------------------------------------------------------

#define SCAN_BLOCK 256
#define CB 128               // keys per coarse bucket
#define CHUNK 4096           // edges per hist/rank block
#define NBC_MAX 800          // >= ceil(2V/CB) = 782
#define CAP 3072             // LDS staging cap per bucket (lambda=1024, 64 sigma)
#define RED1 64              // stage-1 reduce blocks (fixed)
#define NGB 128              // GEMM row-group blocks per column half

typedef __attribute__((ext_vector_type(8))) short short8v;   // 8 bf16
typedef __attribute__((ext_vector_type(4))) float float4v;   // MFMA C/D

__device__ inline short f2bf(float f) {
    union { float f; unsigned u; } c; c.f = f;
    unsigned u = c.u;
    return (short)((u + 0x7fffu + ((u >> 16) & 1u)) >> 16);  // RNE
}
__device__ inline unsigned packbf(float a, float b) {
    return (unsigned)(unsigned short)f2bf(a) |
           ((unsigned)(unsigned short)f2bf(b) << 16);
}
__device__ inline float bflo(unsigned u) { return __uint_as_float(u << 16); }
__device__ inline float bfhi(unsigned u) { return __uint_as_float(u & 0xffff0000u); }

// fused prep: blocks [0,XB) cast x/rel to bf16; [XB,XB+24) pack weights;
// [XB+24, XB+24+NBLK) per-block LDS histogram. All three are independent.
__global__ __launch_bounds__(256) void prep_kernel(
    const float* __restrict__ x, const float* __restrict__ rel,
    short* __restrict__ xbf, short* __restrict__ relbf,
    const float* __restrict__ in_w,
    const float* __restrict__ out_w,
    const float* __restrict__ loop_w,
    const float* __restrict__ loop_rel,
    short* __restrict__ wpack,
    const int* __restrict__ dst, int* __restrict__ counts,
    int V, int R, int E, int NBC, int XB)
{
    int b = blockIdx.x;
    if (b < XB) {
        // --- xcast ---
        size_t i = ((size_t)b * 256 + threadIdx.x) * 8;
        size_t nx = (size_t)V * 128;
        size_t total = nx + (size_t)R * 128;
        if (i >= total) return;
        const float* sp; short* dp; size_t k;
        if (i < nx) { sp = x; dp = xbf; k = i; }
        else        { sp = rel; dp = relbf; k = i - nx; }
        float4 v0 = *reinterpret_cast<const float4*>(sp + k);
        float4 v1 = *reinterpret_cast<const float4*>(sp + k + 4);
        short8v o;
        o[0] = f2bf(v0.x); o[1] = f2bf(v0.y); o[2] = f2bf(v0.z); o[3] = f2bf(v0.w);
        o[4] = f2bf(v1.x); o[5] = f2bf(v1.y); o[6] = f2bf(v1.z); o[7] = f2bf(v1.w);
        *reinterpret_cast<short8v*>(dp + k) = o;
    } else if (b < XB + 24) {
        // --- wpack ---
        int idx = (b - XB) * 256 + threadIdx.x;
        if (idx >= 3 * 8 * 4 * 64) return;
        int lane = idx & 63;
        int t    = (idx >> 6) & 3;
        int cblk = (idx >> 8) & 7;
        int m    = idx >> 11;
        const float* W = (m == 0) ? in_w : (m == 1) ? out_w : loop_w;
        int col = cblk * 16 + (lane & 15);
        int kb  = t * 32 + ((lane >> 4) << 3);
        short8v v;
#pragma unroll
        for (int j = 0; j < 8; ++j) {
            float w = W[(kb + j) * 128 + col];
            if (m == 2) w *= loop_rel[kb + j];
            v[j] = f2bf(w);
        }
        *reinterpret_cast<short8v*>(wpack + (size_t)idx * 8) = v;
    } else {
        // --- hist_coarse ---
        __shared__ int lh[NBC_MAX];
        int hb = b - XB - 24;
        for (int i = threadIdx.x; i < NBC; i += 256) lh[i] = 0;
        __syncthreads();
        int half = E >> 1;
        int e0 = hb * CHUNK;
        for (int i = 0; i < CHUNK / 256; ++i) {
            int e = e0 + i * 256 + threadIdx.x;
            if (e < E) {
                int key = dst[e] + (e < half ? 0 : V);
                atomicAdd(&lh[key >> 7], 1);
            }
        }
        __syncthreads();
        for (int i = threadIdx.x; i < NBC; i += 256)
            counts[(size_t)hb * NBC + i] = lh[i];
    }
}

// scan phase 1, TRANSPOSED read: logical l = bucket*NBLK + blk.
// Writes RAW per-block sums.
__global__ __launch_bounds__(SCAN_BLOCK) void scan_partial_t_kernel(
    const int* __restrict__ cnt_bm, int* __restrict__ partials,
    int CN, int NBC, int NBLK)
{
    __shared__ int red[SCAN_BLOCK];
    int l = blockIdx.x * SCAN_BLOCK + threadIdx.x;
    int v = 0;
    if (l < CN) {
        int bu = l / NBLK, bl = l - bu * NBLK;
        v = cnt_bm[(size_t)bl * NBC + bu];
    }
    red[threadIdx.x] = v;
    __syncthreads();
    for (int s = SCAN_BLOCK / 2; s > 0; s >>= 1) {
        if (threadIdx.x < s) red[threadIdx.x] += red[threadIdx.x + s];
        __syncthreads();
    }
    if (threadIdx.x == 0) partials[blockIdx.x] = red[0];
}

// scan phase 2 (fused): block bid reduces partials[0..bid) itself, then
// does the local Hillis-Steele scan.
__global__ __launch_bounds__(SCAN_BLOCK) void scan_final_t_kernel(
    const int* __restrict__ cnt_bm, const int* __restrict__ partials,
    int* __restrict__ base, int CN, int NBC, int NBLK)
{
    __shared__ int sh[SCAN_BLOCK];
    __shared__ int pref_s;
    int t = threadIdx.x;
    int bid = blockIdx.x;

    int acc = 0;
    for (int i = t; i < bid; i += SCAN_BLOCK) acc += partials[i];
    sh[t] = acc;
    __syncthreads();
    for (int s = SCAN_BLOCK / 2; s > 0; s >>= 1) {
        if (t < s) sh[t] += sh[t + s];
        __syncthreads();
    }
    if (t == 0) pref_s = sh[0];
    __syncthreads();
    int pref = pref_s;
    __syncthreads();   // sh[] reuse

    int l = bid * SCAN_BLOCK + t;
    int v = 0;
    if (l < CN) {
        int bu = l / NBLK, bl = l - bu * NBLK;
        v = cnt_bm[(size_t)bl * NBC + bu];
    }
    sh[t] = v;
    __syncthreads();
    for (int s = 1; s < SCAN_BLOCK; s <<= 1) {
        int u = (t >= s) ? sh[t - s] : 0;
        __syncthreads();
        sh[t] += u;
        __syncthreads();
    }
    if (l < CN) base[l] = pref + sh[t] - v;
}

// scatter payload; per-(bucket,block) runs contiguous, written from one CU.
// payload: (src<<16 | type<<8 | key&127, norm-bits). 512 threads.
__global__ __launch_bounds__(512) void rank_coarse_kernel(
    const int* __restrict__ dst,
    const int* __restrict__ src,
    const int* __restrict__ edge_type,
    const float* __restrict__ edge_norm,
    const int* __restrict__ base,
    uint2* __restrict__ pay,
    int E, int V, int NBC, int NBLK)
{
    __shared__ int lh[NBC_MAX];
    __shared__ int lb[NBC_MAX];
    for (int i = threadIdx.x; i < NBC; i += 512) {
        lh[i] = 0;
        lb[i] = base[(size_t)i * NBLK + blockIdx.x];
    }
    __syncthreads();
    int half = E >> 1;
    int e0 = blockIdx.x * CHUNK;
    for (int i = 0; i < CHUNK / 512; ++i) {
        int e = e0 + i * 512 + threadIdx.x;
        if (e < E) {
            int d = dst[e], s = src[e], t = edge_type[e];
            float n = edge_norm[e];
            int key = d + (e < half ? 0 : V);
            int b = key >> 7;
            int r = atomicAdd(&lh[b], 1);
            pay[lb[b] + r] = make_uint2(
                ((unsigned)s << 16) | ((unsigned)t << 8) | (unsigned)(key & 127),
                __float_as_uint(n));
        }
    }
}

// one block per coarse bucket: LDS counting sort of the bucket's payload;
// writes key-sorted pay2 (coalesced) + per-key CSR foffg [NK+1]. 512 threads.
__global__ __launch_bounds__(512) void fine_sort_kernel(
    const uint2* __restrict__ pay,
    const int* __restrict__ base,
    uint2* __restrict__ pay2,
    int* __restrict__ foffg,
    int E, int NK, int NBC, int NBLK)
{
    __shared__ uint2 pay_s[CAP];     // 24 KB
    __shared__ int fcnt[CB];
    __shared__ int ssc[CB];
    __shared__ int fcur[CB];

    int b = blockIdx.x;
    int beg = base[(size_t)b * NBLK];
    int end = (b + 1 < NBC) ? base[(size_t)(b + 1) * NBLK] : E;
    int cnt = end - beg;
    int tid = threadIdx.x;

    if (tid < CB) fcnt[tid] = 0;
    __syncthreads();
    for (int j = tid; j < cnt; j += 512)
        atomicAdd(&fcnt[pay[beg + j].x & 127u], 1);
    __syncthreads();
    if (tid < CB) ssc[tid] = fcnt[tid];
    __syncthreads();
    for (int s = 1; s < CB; s <<= 1) {
        int v = 0;
        if (tid < CB && tid >= s) v = ssc[tid - s];
        __syncthreads();
        if (tid < CB) ssc[tid] += v;
        __syncthreads();
    }
    if (tid < CB) {
        int ex = ssc[tid] - fcnt[tid];
        fcur[tid] = ex;
        int key = b * CB + tid;
        if (key <= NK) foffg[key] = beg + ex;
    }
    __syncthreads();

    if (cnt <= CAP) {
        for (int j = tid; j < cnt; j += 512) {
            uint2 p = pay[beg + j];
            int r = atomicAdd(&fcur[p.x & 127u], 1);
            pay_s[r] = p;
        }
        __syncthreads();
        for (int j = tid; j < cnt; j += 512) pay2[beg + j] = pay_s[j];
    } else {
        for (int j = tid; j < cnt; j += 512) {
            uint2 p = pay[beg + j];
            int r = atomicAdd(&fcur[p.x & 127u], 1);
            pay2[beg + r] = p;
        }
    }
}

// 16-lane group per key (4 keys/wave): 4 independent edge-gather chains per
// wave, 16B row loads (8 bf16/lane), branch-free tail predication.
__global__ __launch_bounds__(256) void aggregate_g16_kernel(
    const short* __restrict__ xbf,
    const short* __restrict__ relbf,
    const uint2* __restrict__ pay2,
    const int* __restrict__ foffg,
    short* __restrict__ accbf,       // [NK,128]
    int NK, int E)
{
    int wid = (blockIdx.x * 256 + threadIdx.x) >> 6;
    int lane = threadIdx.x & 63;
    int g = lane >> 4;
    int sub = lane & 15;
    int k = wid * 4 + g;
    if (k >= NK) k = NK - 1;
    int f0 = sub << 3;

    int beg = foffg[k];
    int end = foffg[k + 1];
    int cnt = end - beg;

    int maxc = cnt;
    maxc = max(maxc, __shfl_xor(maxc, 16, 64));
    maxc = max(maxc, __shfl_xor(maxc, 32, 64));

    float a0 = 0.f, a1 = 0.f, a2 = 0.f, a3 = 0.f;
    float a4 = 0.f, a5 = 0.f, a6 = 0.f, a7 = 0.f;

    for (int bas = 0; bas < maxc; bas += 16) {
        int off = bas + sub;
        int cidx = (cnt > 0) ? min(off, cnt - 1) : 0;
        int j = min(beg + cidx, E - 1);
        uint2 p = pay2[j];
        int qmax = min(16, maxc - bas);
        for (int q = 0; q < qmax; ++q) {
            int srcl = (lane & 48) + q;
            unsigned pqx = __shfl(p.x, srcl, 64);
            unsigned pqn = __shfl(p.y, srcl, 64);
            float n = ((bas + q) < cnt) ? __uint_as_float(pqn) : 0.f;
            int s = (int)(pqx >> 16);
            int t = (int)((pqx >> 8) & 0xffu);
            uint4 xv = *reinterpret_cast<const uint4*>(xbf + (size_t)s * 128 + f0);
            uint4 rv = *reinterpret_cast<const uint4*>(relbf + (size_t)t * 128 + f0);
            a0 += bflo(xv.x) * bflo(rv.x) * n;
            a1 += bfhi(xv.x) * bfhi(rv.x) * n;
            a2 += bflo(xv.y) * bflo(rv.y) * n;
            a3 += bfhi(xv.y) * bfhi(rv.y) * n;
            a4 += bflo(xv.z) * bflo(rv.z) * n;
            a5 += bfhi(xv.z) * bfhi(rv.z) * n;
            a6 += bflo(xv.w) * bflo(rv.w) * n;
            a7 += bfhi(xv.w) * bfhi(rv.w) * n;
        }
    }
    uint4 o;
    o.x = packbf(a0, a1);
    o.y = packbf(a2, a3);
    o.z = packbf(a4, a5);
    o.w = packbf(a6, a7);
    *reinterpret_cast<uint4*>(accbf + (size_t)k * 128 + f0) = o;
}

// bf16 MFMA fused GEMM + bias + /3; persistent blocks (1/CU):
// 48KB weights staged ONCE, zero-barrier tile loop.
__global__ __launch_bounds__(512) void fused_gemm_mfma_kernel(
    const short* __restrict__ accbf,     // [2V,128]
    const short* __restrict__ xbf,       // [V,128]
    const short* __restrict__ wpack,
    const float* __restrict__ bias,
    short* __restrict__ hbf,             // [V,128] bf16 intermediate
    float* __restrict__ stats_part,      // [NGB][256]
    int V, int NRB)
{
    __shared__ short wlds[3 * 4 * 4 * 64 * 8];   // 48 KB
    __shared__ float s_red[128];                 // [0:64] sum, [64:128] sumsq

    int tid  = threadIdx.x;
    int wave = tid >> 6;
    int lane = tid & 63;
    int kgrp = lane >> 4;
    int r16  = lane & 15;
    int bid  = blockIdx.x >> 1;
    int hh   = blockIdx.x & 1;

    if (tid < 128) s_red[tid] = 0.f;

    {
        const short8v* wsv = reinterpret_cast<const short8v*>(wpack);
        short8v* wldv = reinterpret_cast<short8v*>(wlds);
#pragma unroll
        for (int i = 0; i < 6; ++i) {
            int idx = i * 512 + tid;
            int l  = idx & 63;
            int t  = (idx >> 6) & 3;
            int cb = (idx >> 8) & 3;
            int m  = idx >> 10;
            wldv[idx] = wsv[(((size_t)m * 8 + (4 * hh + cb)) * 4 + t) * 64 + l];
        }
    }
    __syncthreads();   // weights staged; s_red zeroed. NO barriers after this.

    const short8v* wldv = reinterpret_cast<const short8v*>(wlds);
    float ps[4] = {0.f, 0.f, 0.f, 0.f};
    float pq[4] = {0.f, 0.f, 0.f, 0.f};

    for (int rt = bid; rt < NRB; rt += NGB) {
        int row0 = rt * 128 + wave * 16;
        int rowl = row0 + r16;
        int rowc = min(rowl, V - 1);

        short8v af[3][4];
        {
            const short* A0 = accbf + (size_t)rowc * 128;
            const short* A1 = accbf + (size_t)(V + rowc) * 128;
            const short* A2 = xbf + (size_t)rowc * 128;
#pragma unroll
            for (int t = 0; t < 4; ++t) {
                int o = t * 32 + (kgrp << 3);
                af[0][t] = *reinterpret_cast<const short8v*>(A0 + o);
                af[1][t] = *reinterpret_cast<const short8v*>(A1 + o);
                af[2][t] = *reinterpret_cast<const short8v*>(A2 + o);
            }
        }

        float4v c[4];
#pragma unroll
        for (int b = 0; b < 4; ++b) c[b] = (float4v)(0.f);

#pragma unroll
        for (int m = 0; m < 3; ++m)
#pragma unroll
            for (int t = 0; t < 4; ++t) {
#pragma unroll
                for (int b = 0; b < 4; ++b) {
                    short8v bf_ = wldv[(((m * 4 + b) * 4) + t) * 64 + lane];
                    c[b] = __builtin_amdgcn_mfma_f32_16x16x32_bf16(af[m][t], bf_, c[b], 0, 0, 0);
                }
            }

        // epilogue: C/D layout col=lane&15, row=(lane>>4)*4+r  [m89]
#pragma unroll
        for (int b = 0; b < 4; ++b) {
            int col = hh * 64 + b * 16 + r16;
            float bv = bias[col];
#pragma unroll
            for (int r = 0; r < 4; ++r) {
                int row = row0 + kgrp * 4 + r;
                if (row < V) {
                    float v = c[b][r] * (1.f / 3.f) + bv;
                    hbf[(size_t)row * 128 + col] = f2bf(v);
                    ps[b] += v;
                    pq[b] += v * v;
                }
            }
        }
    }

#pragma unroll
    for (int b = 0; b < 4; ++b) {
        int cl = b * 16 + r16;
        atomicAdd(&s_red[cl], ps[b]);
        atomicAdd(&s_red[64 + cl], pq[b]);
    }
    __syncthreads();
    if (tid < 64)
        stats_part[(size_t)bid * 256 + hh * 64 + tid] = s_red[tid];
    else if (tid < 128)
        stats_part[(size_t)bid * 256 + 128 + hh * 64 + (tid - 64)] = s_red[tid];
}

// BN reduce stage 1: 64 blocks, each sums a strided subset of NB partials
__global__ __launch_bounds__(256) void bn_reduce1_kernel(
    const float* __restrict__ stats_part, float* __restrict__ stage, int NB)
{
    int col = threadIdx.x;
    float s = 0.f;
    for (int i = blockIdx.x; i < NB; i += RED1)
        s += stats_part[(size_t)i * 256 + col];
    stage[(size_t)blockIdx.x * 256 + col] = s;
}

// fused: per-block stats finalize + BN apply + ReLU (bf16 in, f32 out);
// blocks >= NBA compute out_rel = rel @ w_rel.
__global__ __launch_bounds__(256) void bn_apply_fused_kernel(
    const short* __restrict__ hbf,
    float* __restrict__ hout,
    const float* __restrict__ stage,
    const float* __restrict__ gamma,
    const float* __restrict__ beta,
    int V, int NBA,
    const float* __restrict__ rel,
    const float* __restrict__ w_rel,
    float* __restrict__ out_rel,
    int R)
{
    int tid = threadIdx.x;
    if ((int)blockIdx.x >= NBA) {
        int rb = blockIdx.x - NBA;
        int col = tid & 127;
        int row = rb * 2 + (tid >> 7);
        if (row >= R) return;
        float acc = 0.f;
        for (int k = 0; k < 128; ++k)
            acc += rel[row * 128 + k] * w_rel[k * 128 + col];
        out_rel[row * 128 + col] = acc;
        return;
    }

    __shared__ float st[256];
    {
        float s0 = 0.f, s1 = 0.f, s2 = 0.f, s3 = 0.f;
#pragma unroll
        for (int i = 0; i < RED1; i += 4) {
            s0 += stage[(size_t)(i + 0) * 256 + tid];
            s1 += stage[(size_t)(i + 1) * 256 + tid];
            s2 += stage[(size_t)(i + 2) * 256 + tid];
            s3 += stage[(size_t)(i + 3) * 256 + tid];
        }
        st[tid] = (s0 + s1) + (s2 + s3);
    }
    __syncthreads();

    int c4   = (tid & 31) << 2;
    int rsub = tid >> 5;
    float inv_v = 1.f / (float)V;
    float sc[4], sh[4];
#pragma unroll
    for (int j = 0; j < 4; ++j) {
        int col = c4 + j;
        float mean = st[col] * inv_v;
        float var  = st[128 + col] * inv_v - mean * mean;
        float s = rsqrtf(var + 1e-5f) * gamma[col];
        sc[j] = s;
        sh[j] = beta[col] - mean * s;
    }
    for (int row = blockIdx.x * 8 + rsub; row < V; row += NBA * 8) {
        uint2 u = *reinterpret_cast<const uint2*>(hbf + (size_t)row * 128 + c4);
        float4 v;
        v.x = fmaxf(bflo(u.x) * sc[0] + sh[0], 0.f);
        v.y = fmaxf(bfhi(u.x) * sc[1] + sh[1], 0.f);
        v.z = fmaxf(bflo(u.y) * sc[2] + sh[2], 0.f);
        v.w = fmaxf(bfhi(u.y) * sc[3] + sh[3], 0.f);
        *reinterpret_cast<float4*>(hout + (size_t)row * 128 + c4) = v;
    }
}

extern "C" void kernel_launch(void* const* d_in, const int* in_sizes, int n_in,
                              void* d_out, int out_size, void* d_ws, size_t ws_size,
                              hipStream_t stream)
{
    const float* x         = (const float*)d_in[0];
    const float* rel_repr  = (const float*)d_in[1];
    const float* edge_norm = (const float*)d_in[2];
    const float* in_w      = (const float*)d_in[3];
    const float* out_w     = (const float*)d_in[4];
    const float* loop_w    = (const float*)d_in[5];
    const float* w_rel     = (const float*)d_in[6];
    const float* loop_rel  = (const float*)d_in[7];
    const float* bias      = (const float*)d_in[8];
    const float* bn_gamma  = (const float*)d_in[9];
    const float* bn_beta   = (const float*)d_in[10];
    const int* edge_type   = (const int*)d_in[11];
    const int* src         = (const int*)d_in[12];
    const int* dst         = (const int*)d_in[13];

    const int V = in_sizes[0] / 128;     // 50000
    const int E = in_sizes[2];           // 800000
    const int R = in_sizes[1] / 128;     // 200
    const int NK = 2 * V;                // keys: [dst(in) ; dst(out)]
    const int NBC = (NK + CB - 1) / CB;              // coarse buckets (782)
    const int NBLK = (E + CHUNK - 1) / CHUNK;        // hist/rank blocks (196)
    const int CN = NBC * NBLK;                       // scan length
    const int NB2 = (CN + SCAN_BLOCK - 1) / SCAN_BLOCK;
    const int NRB = (V + 127) / 128;                 // GEMM row tiles (391)
    const int NBA = 256;                             // bn_apply blocks
    const int XB  = (int)((((size_t)(V + R) * 128) / 8 + 255) / 256);  // xcast blocks

    float* hout    = (float*)d_out;              // [V,128]
    float* out_rel = hout + (size_t)V * 128;     // [R,128]

    // workspace layout
    char* wp_ = (char*)d_ws;
    short* accbf    = (short*)wp_;  wp_ += (size_t)NK * 128 * sizeof(short);
    short* xbf      = (short*)wp_;  wp_ += (size_t)V * 128 * sizeof(short);
    short* relbf    = (short*)wp_;  wp_ += (size_t)R * 128 * sizeof(short);
    short* hbf      = (short*)wp_;  wp_ += (size_t)V * 128 * sizeof(short);
    short* wpack    = (short*)wp_;  wp_ += (size_t)3 * 8 * 4 * 64 * 8 * sizeof(short);
    float* stats_pt = (float*)wp_;  wp_ += (size_t)NGB * 256 * sizeof(float);
    float* stage    = (float*)wp_;  wp_ += (size_t)RED1 * 256 * sizeof(float);
    int*   counts   = (int*)wp_;    wp_ += (size_t)CN * sizeof(int);   // block-major
    int*   basep    = (int*)wp_;    wp_ += (size_t)CN * sizeof(int);   // bucket-major
    int*   partials = (int*)wp_;    wp_ += 1024 * sizeof(int);
    int*   foffg    = (int*)wp_;    wp_ += ((size_t)NK + 2) * sizeof(int);
    wp_ = (char*)(((uintptr_t)wp_ + 15) & ~(uintptr_t)15);
    uint2* pay      = (uint2*)wp_;  wp_ += (size_t)E * sizeof(uint2);
    uint2* pay2     = (uint2*)wp_;

    // NOTE: no memset needed — every consumed workspace buffer is fully
    // written each call.

    prep_kernel<<<XB + 24 + NBLK, 256, 0, stream>>>(
        x, rel_repr, xbf, relbf,
        in_w, out_w, loop_w, loop_rel, wpack,
        dst, counts, V, R, E, NBC, XB);

    scan_partial_t_kernel<<<NB2, SCAN_BLOCK, 0, stream>>>(counts, partials, CN, NBC, NBLK);
    scan_final_t_kernel<<<NB2, SCAN_BLOCK, 0, stream>>>(counts, partials, basep, CN, NBC, NBLK);
    rank_coarse_kernel<<<NBLK, 512, 0, stream>>>(
        dst, src, edge_type, edge_norm, basep, pay, E, V, NBC, NBLK);
    fine_sort_kernel<<<NBC, 512, 0, stream>>>(
        pay, basep, pay2, foffg, E, NK, NBC, NBLK);

    {
        int waves = (NK + 3) / 4;                        // 25000
        int blocks = (waves * 64 + 255) / 256;           // 6250
        aggregate_g16_kernel<<<blocks, 256, 0, stream>>>(
            xbf, relbf, pay2, foffg, accbf, NK, E);
    }

    fused_gemm_mfma_kernel<<<NGB * 2, 512, 0, stream>>>(
        accbf, xbf, wpack, bias, hbf, stats_pt, V, NRB);

    bn_reduce1_kernel<<<RED1, 256, 0, stream>>>(stats_pt, stage, NGB);
    bn_apply_fused_kernel<<<NBA + (R + 1) / 2, 256, 0, stream>>>(
        hbf, hout, stage, bn_gamma, bn_beta, V, NBA,
        rel_repr, w_rel, out_rel, R);
}